// Round 1
// 330.470 us; speedup vs baseline: 1.0614x; 1.0614x over previous
//
#include <hip/hip_runtime.h>
#include <stdint.h>

// CrossAttention via linear-attention algebra, both halves merged to M=16384:
//   S = K1^T V1 + K2^T V2 (per b,h; 64x64), shared by both halves.
//   attn = Q @ S ; x = LN(inp + attn@Wo^T + bo) ; out = LN(x + FF(x))
// bf16 MFMA GEMMs, BK=64, XOR-swizzled LDS staging (R8: 0 bank conflicts).
// R9: LDS-staged coalesced epilogues (write amplification fix).
// R10: s_kernel rewrite — old version was latency-bound (55 us, VALUBusy 14%,
// 8-row tiles = 64 barriers/block, scalar 2B loads, 2M atomicAdds -> 33 MB
// write traffic). New: 64-row fp32 LDS tiles, ushort8 16B loads, 8 barriers,
// per-block 64x64 fp32 partials to Spart (reuses attnb region, dead until
// attn_mfma); sbt_convert reduces 16 slices during the bf16 B-layout pack.
// VALU floor ~7 us; predicted ~10 us.

#define Bq 4
#define Lq 2048
#define Dq 512
#define PFq 2048
#define Mrows 16384
#define MiBu 1048576ull
#define NSLICE 16

typedef __attribute__((ext_vector_type(8))) short frag_ab;
typedef __attribute__((ext_vector_type(4))) float frag_cd;
typedef __attribute__((ext_vector_type(8))) unsigned short ushort8v;

__device__ __forceinline__ unsigned short f2b(float f) {
    union { float f; uint32_t u; } x; x.f = f;
    uint32_t r = x.u + 0x7fffu + ((x.u >> 16) & 1u);
    return (unsigned short)(r >> 16);
}
__device__ __forceinline__ float b2f(unsigned short u) {
    union { uint32_t u; float f; } x; x.u = ((uint32_t)u) << 16;
    return x.f;
}

#define GLD16(g, l)                                                              \
    __builtin_amdgcn_global_load_lds(                                            \
        (const __attribute__((address_space(1))) void*)(const void*)(g),         \
        (__attribute__((address_space(3))) void*)(void*)(l), 16, 0, 0)

// ---------- bf16 MFMA GEMM: outB = A[M,K]b @ W[N,K]b^T + bias (+relu) ----------
// 128x128 tile, BK=64; grid (M/128, N/128), block 256
__global__ __launch_bounds__(256) void gemm_bf16(
    const unsigned short* __restrict__ A, const unsigned short* __restrict__ Wt,
    const float* __restrict__ bias, unsigned short* __restrict__ outB,
    int M, int N, int K, int relu)
{
    __shared__ __align__(16) unsigned short Sh[2 * 128 * 64];
    unsigned short* At = Sh;
    unsigned short* Bt = Sh + 128 * 64;
    const int tid = threadIdx.x;
    const int lane = tid & 63;
    const int w = tid >> 6;
    const int wm = (w >> 1) * 64, wn = (w & 1) * 64;
    const int lr = lane & 15;
    const int quad = lane >> 4;
    const size_t bm = (size_t)blockIdx.x * 128, bn = (size_t)blockIdx.y * 128;

    frag_cd acc[4][4] = {};

    const int ar = tid >> 3;
    const int acs = (((tid & 7) ^ (ar & 7)) << 3);
    const unsigned short* Ag = A  + (bm + ar) * (size_t)K + acs;
    const unsigned short* Bg = Wt + (bn + ar) * (size_t)K + acs;
    unsigned short* Asd = At + w * 512;
    unsigned short* Bsd = Bt + w * 512;

    for (int k0 = 0; k0 < K; k0 += 64) {
        __syncthreads();
#pragma unroll
        for (int i = 0; i < 4; ++i) {
            GLD16(Ag + (size_t)(32 * i) * K + k0, Asd + i * 2048);
            GLD16(Bg + (size_t)(32 * i) * K + k0, Bsd + i * 2048);
        }
        __syncthreads();
#pragma unroll
        for (int kk = 0; kk < 2; ++kk) {
            frag_ab a[4], b[4];
#pragma unroll
            for (int i = 0; i < 4; ++i)
                a[i] = *(const frag_ab*)&At[(wm + i * 16 + lr) * 64 +
                                            ((((kk << 2) | quad) ^ (lr & 7)) << 3)];
#pragma unroll
            for (int j = 0; j < 4; ++j)
                b[j] = *(const frag_ab*)&Bt[(wn + j * 16 + lr) * 64 +
                                            ((((kk << 2) | quad) ^ (lr & 7)) << 3)];
#pragma unroll
            for (int i = 0; i < 4; ++i)
#pragma unroll
                for (int j = 0; j < 4; ++j)
                    acc[i][j] = __builtin_amdgcn_mfma_f32_16x16x32_bf16(a[i], b[j], acc[i][j], 0, 0, 0);
        }
    }

    // LDS-staged epilogue: wave w owns Sh[w*4096 .. +4096) = 64x64 bf16
    __syncthreads();
    unsigned short* Cs = Sh + w * 4096;
#pragma unroll
    for (int j = 0; j < 4; ++j) {
        const float bv = bias[(int)bn + wn + j * 16 + lr];
#pragma unroll
        for (int i = 0; i < 4; ++i)
#pragma unroll
            for (int r = 0; r < 4; ++r) {
                float v = acc[i][j][r] + bv;
                if (relu) v = fmaxf(v, 0.f);
                Cs[(i * 16 + quad * 4 + r) * 64 + j * 16 + lr] = f2b(v);
            }
    }
    const int rl = lane >> 3;            // 0..7
    const int c8 = (lane & 7) * 8;       // col chunk base
#pragma unroll
    for (int k = 0; k < 8; ++k) {
        const int row = rl + k * 8;
        ushort8v val = *(const ushort8v*)&Cs[row * 64 + c8];
        *(ushort8v*)(outB + (size_t)(bm + wm + row) * N + bn + wn + c8) = val;
    }
}

// ---------- narrow-N residual GEMM: 128x64 tile, BK=64 -------------------------
// outB = A@W^T + bias + residual. resA/resB f32 (rows <8192 / >=8192).
// resA==null: residual = b2f(outB[idx]) (in-place). grid (M/128, N/64).
__global__ __launch_bounds__(256) void gemm_res(
    const unsigned short* __restrict__ A, const unsigned short* __restrict__ Wt,
    const float* __restrict__ bias,
    const float* __restrict__ resA, const float* __restrict__ resB,
    unsigned short* __restrict__ outB, int M, int N, int K)
{
    __shared__ __align__(16) unsigned short Sh[128 * 64 + 64 * 64];
    unsigned short* At = Sh;
    unsigned short* Bt = Sh + 128 * 64;
    const int tid = threadIdx.x;
    const int lane = tid & 63;
    const int w = tid >> 6;
    const int wm = w * 32;
    const int lr = lane & 15;
    const int quad = lane >> 4;
    const size_t bm = (size_t)blockIdx.x * 128, bn = (size_t)blockIdx.y * 64;

    frag_cd acc[2][4] = {};

    const int ar = tid >> 3;
    const int acs = (((tid & 7) ^ (ar & 7)) << 3);
    const unsigned short* Ag = A  + (bm + ar) * (size_t)K + acs;
    const unsigned short* Bg = Wt + (bn + ar) * (size_t)K + acs;
    unsigned short* Asd = At + w * 512;
    unsigned short* Bsd = Bt + w * 512;

    for (int k0 = 0; k0 < K; k0 += 64) {
        __syncthreads();
#pragma unroll
        for (int i = 0; i < 4; ++i)
            GLD16(Ag + (size_t)(32 * i) * K + k0, Asd + i * 2048);
#pragma unroll
        for (int i = 0; i < 2; ++i)
            GLD16(Bg + (size_t)(32 * i) * K + k0, Bsd + i * 2048);
        __syncthreads();
#pragma unroll
        for (int kk = 0; kk < 2; ++kk) {
            frag_ab a[2], b[4];
#pragma unroll
            for (int i = 0; i < 2; ++i)
                a[i] = *(const frag_ab*)&At[(wm + i * 16 + lr) * 64 +
                                            ((((kk << 2) | quad) ^ (lr & 7)) << 3)];
#pragma unroll
            for (int j = 0; j < 4; ++j)
                b[j] = *(const frag_ab*)&Bt[(j * 16 + lr) * 64 +
                                            ((((kk << 2) | quad) ^ (lr & 7)) << 3)];
#pragma unroll
            for (int i = 0; i < 2; ++i)
#pragma unroll
                for (int j = 0; j < 4; ++j)
                    acc[i][j] = __builtin_amdgcn_mfma_f32_16x16x32_bf16(a[i], b[j], acc[i][j], 0, 0, 0);
        }
    }

    // LDS-staged epilogue: wave w owns Sh[w*2048 .. +2048) = 32x64 bf16
    __syncthreads();
    unsigned short* Cs = Sh + w * 2048;
#pragma unroll
    for (int j = 0; j < 4; ++j) {
        const float bv = bias[(int)bn + j * 16 + lr];
#pragma unroll
        for (int i = 0; i < 2; ++i)
#pragma unroll
            for (int r = 0; r < 4; ++r)
                Cs[(i * 16 + quad * 4 + r) * 64 + j * 16 + lr] = f2b(acc[i][j][r] + bv);
    }
    const int rl = lane >> 3;
    const int c8 = (lane & 7) * 8;
#pragma unroll
    for (int k = 0; k < 4; ++k) {
        const int row = rl + k * 8;
        const int grow = (int)bm + wm + row;
        const size_t idx = (size_t)grow * N + bn + c8;
        ushort8v val = *(const ushort8v*)&Cs[row * 64 + c8];
        float vv[8];
#pragma unroll
        for (int t = 0; t < 8; ++t) vv[t] = b2f(val[t]);
        if (resA) {
            const float* rp = (grow < 8192) ? resA + idx : resB + idx - (size_t)8192 * N;
            float4 ra = *(const float4*)(rp);
            float4 rb = *(const float4*)(rp + 4);
            vv[0] += ra.x; vv[1] += ra.y; vv[2] += ra.z; vv[3] += ra.w;
            vv[4] += rb.x; vv[5] += rb.y; vv[6] += rb.z; vv[7] += rb.w;
        } else {
            ushort8v old = *(const ushort8v*)(outB + idx);
#pragma unroll
            for (int t = 0; t < 8; ++t) vv[t] += b2f(old[t]);
        }
        ushort8v o;
#pragma unroll
        for (int t = 0; t < 8; ++t) o[t] = f2b(vv[t]);
        *(ushort8v*)(outB + idx) = o;
    }
}

// -------- merged fp32->bf16 converts + QKV bias concat --------
__global__ __launch_bounds__(256) void convert_all(
    const float* __restrict__ Wq, const float* __restrict__ Wk,
    const float* __restrict__ Wv, const float* __restrict__ Wo,
    const float* __restrict__ W1, const float* __restrict__ W2,
    const float* __restrict__ question, const float* __restrict__ query,
    const float* __restrict__ bqp, const float* __restrict__ bkp,
    const float* __restrict__ bvp,
    unsigned short* __restrict__ Wqkvb, unsigned short* __restrict__ Wob,
    unsigned short* __restrict__ W1b, unsigned short* __restrict__ W2b,
    unsigned short* __restrict__ Xb, float* __restrict__ bqkv)
{
    const int b = blockIdx.x;
    const float* src; unsigned short* dst; size_t off;
    if (b < 256)        { src = Wq; dst = Wqkvb;          off = (size_t)b * 1024; }
    else if (b < 512)   { src = Wk; dst = Wqkvb + 262144; off = (size_t)(b - 256) * 1024; }
    else if (b < 768)   { src = Wv; dst = Wqkvb + 524288; off = (size_t)(b - 512) * 1024; }
    else if (b < 1024)  { src = Wo; dst = Wob;            off = (size_t)(b - 768) * 1024; }
    else if (b < 2048)  { src = W1; dst = W1b;            off = (size_t)(b - 1024) * 1024; }
    else if (b < 3072)  { src = W2; dst = W2b;            off = (size_t)(b - 2048) * 1024; }
    else if (b < 7168)  { src = question; dst = Xb;       off = (size_t)(b - 3072) * 1024; }
    else if (b < 11264) { src = query; dst = Xb + 4194304; off = (size_t)(b - 7168) * 1024; }
    else {
        const int n = (b - 11264) * 256 + threadIdx.x;   // 0..1535
        bqkv[n] = (n < 512) ? bqp[n] : (n < 1024) ? bkp[n - 512] : bvp[n - 1024];
        return;
    }
    const size_t idx = off + threadIdx.x * 4;
    float4 v = *(const float4*)(src + idx);
    ushort4 o;
    o.x = f2b(v.x); o.y = f2b(v.y); o.z = f2b(v.z); o.w = f2b(v.w);
    *(ushort4*)(dst + idx) = o;
}

// ------- Spart[bh][slice] = sum over 256 l-rows of K^T outer V (merged QKV) ----
// grid (32 bh, NSLICE); 64-row fp32 LDS tiles, ushort8 loads, no atomics.
__global__ __launch_bounds__(256) void s_kernel(
    const unsigned short* __restrict__ QKV, float* __restrict__ Spart)
{
    const int bh = blockIdx.x;           // 0..31
    const int sl = blockIdx.y;           // 0..NSLICE-1
    const int b = bh >> 3, h = bh & 7;
    const int pass = sl >> 3;            // 0: question half, 1: query half
    const int l0 = (sl & 7) * 256;       // row offset within the half
    __shared__ float Ks[64][64];
    __shared__ float Vs[64][64];
    const int tid = threadIdx.x;
    const int tx = tid & 15, ty = tid >> 4;
    const int srow = tid >> 3;           // 0..31
    const int scol = (tid & 7) * 8;      // 0..56
    const size_t rowbase = (size_t)pass * 8192 + (size_t)b * Lq + l0;

    float acc[4][4] = {};

    for (int t0 = 0; t0 < 256; t0 += 64) {
        // issue global loads for 64 rows (2 x 32) before the barrier so the
        // HBM latency overlaps the previous stage's compute drain
        const unsigned short* kp0 = QKV + (rowbase + t0 + srow) * 1536 + 512 + h * 64 + scol;
        const unsigned short* kp1 = kp0 + (size_t)32 * 1536;
        ushort8v k0 = *(const ushort8v*)kp0;
        ushort8v v0 = *(const ushort8v*)(kp0 + 512);
        ushort8v k1 = *(const ushort8v*)kp1;
        ushort8v v1 = *(const ushort8v*)(kp1 + 512);
        __syncthreads();
#pragma unroll
        for (int e = 0; e < 8; ++e) {
            Ks[srow][scol + e]      = b2f(k0[e]);
            Vs[srow][scol + e]      = b2f(v0[e]);
            Ks[srow + 32][scol + e] = b2f(k1[e]);
            Vs[srow + 32][scol + e] = b2f(v1[e]);
        }
        __syncthreads();
#pragma unroll 4
        for (int rr = 0; rr < 64; ++rr) {
            const float4 kf = *(const float4*)&Ks[rr][ty * 4];
            const float4 vf = *(const float4*)&Vs[rr][tx * 4];
            acc[0][0] = fmaf(kf.x, vf.x, acc[0][0]);
            acc[0][1] = fmaf(kf.x, vf.y, acc[0][1]);
            acc[0][2] = fmaf(kf.x, vf.z, acc[0][2]);
            acc[0][3] = fmaf(kf.x, vf.w, acc[0][3]);
            acc[1][0] = fmaf(kf.y, vf.x, acc[1][0]);
            acc[1][1] = fmaf(kf.y, vf.y, acc[1][1]);
            acc[1][2] = fmaf(kf.y, vf.z, acc[1][2]);
            acc[1][3] = fmaf(kf.y, vf.w, acc[1][3]);
            acc[2][0] = fmaf(kf.z, vf.x, acc[2][0]);
            acc[2][1] = fmaf(kf.z, vf.y, acc[2][1]);
            acc[2][2] = fmaf(kf.z, vf.z, acc[2][2]);
            acc[2][3] = fmaf(kf.z, vf.w, acc[2][3]);
            acc[3][0] = fmaf(kf.w, vf.x, acc[3][0]);
            acc[3][1] = fmaf(kf.w, vf.y, acc[3][1]);
            acc[3][2] = fmaf(kf.w, vf.z, acc[3][2]);
            acc[3][3] = fmaf(kf.w, vf.w, acc[3][3]);
        }
    }

    // coalesced fp32 partial store: thread (tx,ty) owns S[ty*4+i][tx*4+j]
    float* Sp = Spart + ((size_t)bh * NSLICE + sl) * 4096;
#pragma unroll
    for (int i = 0; i < 4; ++i) {
        float4 o = make_float4(acc[i][0], acc[i][1], acc[i][2], acc[i][3]);
        *(float4*)(Sp + (ty * 4 + i) * 64 + tx * 4) = o;
    }
}

// ------- reduce NSLICE partials -> Sbt bf16, B-layout [bh][khalf][n][kj] -------
// grid (32, 4)
__global__ __launch_bounds__(256) void sbt_convert(
    const float* __restrict__ Spart, unsigned short* __restrict__ Sbt)
{
    const int bh = blockIdx.x;
    const int uo = blockIdx.y;           // 0..3
    const float* Sp = Spart + (size_t)bh * (NSLICE * 4096);
    unsigned short* Dp = Sbt + (size_t)bh * 4096;
    const int t = threadIdx.x;
#pragma unroll
    for (int u = 0; u < 4; ++u) {
        const int d = (uo * 4 + u) * 256 + t;    // element of row-major S[64][64]
        float v = 0.f;
#pragma unroll
        for (int s = 0; s < NSLICE; ++s) v += Sp[(size_t)s * 4096 + d];
        const int row = d >> 6, col = d & 63;    // row = dk, col = n
        Dp[(row >> 5) * 2048 + col * 32 + (row & 31)] = f2b(v);
    }
}

// ------- attn = Q @ S_bh via MFMA; block: 128 rows x 64 cols (one head) -------
__global__ __launch_bounds__(256) void attn_mfma(
    const unsigned short* __restrict__ QKV, const unsigned short* __restrict__ Sbt,
    unsigned short* __restrict__ Ob)
{
    __shared__ __align__(16) unsigned short Sh[2 * 128 * 32 + 2 * 64 * 32];
    unsigned short* At = Sh;
    unsigned short* Bt = Sh + 2 * 128 * 32;
    const int h = blockIdx.x;
    const int rbase = blockIdx.y * 128;
    const int b = (rbase >> 11) & 3;
    const int bh = b * 8 + h;
    const int tid = threadIdx.x;
    const int lane = tid & 63;
    const int w = tid >> 6;
    const int lr = lane & 15;
    const int quad = lane >> 4;

    {
        const int rloc = tid >> 2, c8 = (tid & 3) * 8;
#pragma unroll
        for (int it = 0; it < 4; ++it) {
            const int kk = it & 1, rh = it >> 1;
            const unsigned short* g = QKV +
                ((size_t)rbase + rh * 64 + rloc) * 1536 + h * 64 + kk * 32 + c8;
            GLD16(g, At + kk * 4096 + rh * 2048 + w * 512);
        }
        const unsigned short* Sg = Sbt + (size_t)bh * 4096 + tid * 8;
#pragma unroll
        for (int bi = 0; bi < 2; ++bi)
            GLD16(Sg + bi * 2048, Bt + bi * 2048 + w * 512);
    }
    __syncthreads();

    frag_cd acc[2][4] = {};
#pragma unroll
    for (int kk = 0; kk < 2; ++kk) {
        frag_ab a[2], bfr[4];
#pragma unroll
        for (int i = 0; i < 2; ++i)
            a[i] = *(const frag_ab*)&At[kk * 4096 + (w * 32 + i * 16 + lr) * 32 + quad * 8];
#pragma unroll
        for (int j = 0; j < 4; ++j)
            bfr[j] = *(const frag_ab*)&Bt[kk * 2048 + (j * 16 + lr) * 32 + quad * 8];
#pragma unroll
        for (int i = 0; i < 2; ++i)
#pragma unroll
            for (int j = 0; j < 4; ++j)
                acc[i][j] = __builtin_amdgcn_mfma_f32_16x16x32_bf16(a[i], bfr[j], acc[i][j], 0, 0, 0);
    }

    // LDS-staged epilogue: wave w owns Sh[w*2048 .. +2048) = 32x64 bf16
    __syncthreads();
    unsigned short* Cs = Sh + w * 2048;
#pragma unroll
    for (int i = 0; i < 2; ++i)
#pragma unroll
        for (int j = 0; j < 4; ++j)
#pragma unroll
            for (int r = 0; r < 4; ++r)
                Cs[(i * 16 + quad * 4 + r) * 64 + j * 16 + lr] = f2b(acc[i][j][r]);
    const int rl = lane >> 3;
    const int c8o = (lane & 7) * 8;
#pragma unroll
    for (int k = 0; k < 4; ++k) {
        const int row = rl + k * 8;
        ushort8v val = *(const ushort8v*)&Cs[row * 64 + c8o];
        *(ushort8v*)(Ob + (size_t)(rbase + w * 32 + row) * 512 + h * 64 + c8o) = val;
    }
}

// ------- LN over bf16 row (512) in place; wave-shuffle reduction -------
__global__ __launch_bounds__(256) void ln_b16_inplace(
    unsigned short* __restrict__ Y, const float* __restrict__ g,
    const float* __restrict__ bta)
{
    __shared__ float part[8];
    const int row = blockIdx.x;
    const int t = threadIdx.x;
    const int w = t >> 6;
    unsigned short* yr = Y + (size_t)row * Dq;
    const float v0 = b2f(yr[t]), v1 = b2f(yr[t + 256]);
    float s = v0 + v1;
#pragma unroll
    for (int off = 32; off; off >>= 1) s += __shfl_xor(s, off, 64);
    if ((t & 63) == 0) part[w] = s;
    __syncthreads();
    const float mean = (part[0] + part[1] + part[2] + part[3]) * (1.f / Dq);
    const float d0 = v0 - mean, d1 = v1 - mean;
    float q = d0 * d0 + d1 * d1;
#pragma unroll
    for (int off = 32; off; off >>= 1) q += __shfl_xor(q, off, 64);
    if ((t & 63) == 0) part[4 + w] = q;
    __syncthreads();
    const float rstd = rsqrtf((part[4] + part[5] + part[6] + part[7]) * (1.f / Dq) + 1e-5f);
    yr[t] = f2b(d0 * rstd * g[t] + bta[t]);
    yr[t + 256] = f2b(d1 * rstd * g[t + 256] + bta[t + 256]);
}

// ------- LN over bf16 row -> out f32 half-columns (merged rows) -------
__global__ __launch_bounds__(256) void ln_b16_out(
    const unsigned short* __restrict__ Y, const float* __restrict__ g,
    const float* __restrict__ bta, float* __restrict__ out)
{
    __shared__ float part[8];
    const int row = blockIdx.x;
    const int t = threadIdx.x;
    const int w = t >> 6;
    const unsigned short* yr = Y + (size_t)row * Dq;
    const float v0 = b2f(yr[t]), v1 = b2f(yr[t + 256]);
    float s = v0 + v1;
#pragma unroll
    for (int off = 32; off; off >>= 1) s += __shfl_xor(s, off, 64);
    if ((t & 63) == 0) part[w] = s;
    __syncthreads();
    const float mean = (part[0] + part[1] + part[2] + part[3]) * (1.f / Dq);
    const float d0 = v0 - mean, d1 = v1 - mean;
    float q = d0 * d0 + d1 * d1;
#pragma unroll
    for (int off = 32; off; off >>= 1) q += __shfl_xor(q, off, 64);
    if ((t & 63) == 0) part[4 + w] = q;
    __syncthreads();
    const float rstd = rsqrtf((part[4] + part[5] + part[6] + part[7]) * (1.f / Dq) + 1e-5f);
    const int half = row >> 13, br = row & 8191;
    float* orow = out + (size_t)br * 1024 + half * 512;
    orow[t] = d0 * rstd * g[t] + bta[t];
    orow[t + 256] = d1 * rstd * g[t + 256] + bta[t + 256];
}

extern "C" void kernel_launch(void* const* d_in, const int* in_sizes, int n_in,
                              void* d_out, int out_size, void* d_ws, size_t ws_size,
                              hipStream_t stream)
{
    const float* question = (const float*)d_in[0];
    const float* query    = (const float*)d_in[1];
    const float* Wq = (const float*)d_in[2];  const float* bqp = (const float*)d_in[3];
    const float* Wk = (const float*)d_in[4];  const float* bkp = (const float*)d_in[5];
    const float* Wv = (const float*)d_in[6];  const float* bvp = (const float*)d_in[7];
    const float* Wo = (const float*)d_in[8];  const float* bo  = (const float*)d_in[9];
    const float* ln_g = (const float*)d_in[10]; const float* ln_b = (const float*)d_in[11];
    const float* W1 = (const float*)d_in[12]; const float* b1 = (const float*)d_in[13];
    const float* W2 = (const float*)d_in[14]; const float* b2 = (const float*)d_in[15];
    float* out = (float*)d_out;
    char* ws = (char*)d_ws;

    // ---- workspace (~87 MiB) ----
    unsigned short* QKVb  = (unsigned short*)(ws);
    unsigned short* attnb = (unsigned short*)(ws + 48 * MiBu);
    float* Spart          = (float*)(ws + 48 * MiBu);           // 8.4 MiB, dead before attnb
    unsigned short* Xb    = (unsigned short*)(ws + 64 * MiBu);
    unsigned short* xbuf  = (unsigned short*)(ws + 64 * MiBu);  // y0b -> xb -> y
    unsigned short* hb    = (unsigned short*)(ws);              // [16384,2048] bf16
    char* wp = ws + 80 * MiBu + 524288;
    unsigned short* Wqkvb = (unsigned short*)wp;  wp += 1536 * 512 * 2;
    unsigned short* Wob   = (unsigned short*)wp;  wp += 512 * 512 * 2;
    unsigned short* W1b   = (unsigned short*)wp;  wp += 2048 * 512 * 2;
    unsigned short* W2b   = (unsigned short*)wp;  wp += 512 * 2048 * 2;
    unsigned short* Sbt   = (unsigned short*)wp;  wp += 32 * 4096 * 2;
    float* bqkv           = (float*)wp;

    dim3 blk(256);

    convert_all<<<11270, blk, 0, stream>>>(Wq, Wk, Wv, Wo, W1, W2, question, query,
                                           bqp, bkp, bvp,
                                           Wqkvb, Wob, W1b, W2b, Xb, bqkv);

    // QKV: [16384,512]@[1536,512]^T -> bf16; M-major grid (1536 blocks)
    gemm_bf16<<<dim3(128, 12), blk, 0, stream>>>(Xb, Wqkvb, bqkv, QKVb,
                                                 Mrows, 1536, 512, 0);

    // S partials (fp32, no atomics) -> reduce+pack bf16 B-layout; attn via MFMA
    s_kernel<<<dim3(32, NSLICE), blk, 0, stream>>>(QKVb, Spart);
    sbt_convert<<<dim3(32, 4), blk, 0, stream>>>(Spart, Sbt);
    attn_mfma<<<dim3(8, 128), blk, 0, stream>>>(QKVb, Sbt, attnb);

    // o-proj + residual(inputs) + bo -> bf16 y0b (128x64 tiles, 1024 blocks)
    gemm_res<<<dim3(128, 8), blk, 0, stream>>>(attnb, Wob, bo, question, query,
                                               xbuf, Mrows, 512, 512);

    // LN1 in place: xb = LN(y0b)
    ln_b16_inplace<<<Mrows, blk, 0, stream>>>(xbuf, ln_g, ln_b);

    // FFN1 full-M: h = relu(xb @ W1^T + b1) -> bf16 [16384,2048] (2048 blocks)
    gemm_bf16<<<dim3(128, 16), blk, 0, stream>>>(xbuf, W1b, b1, hb,
                                                 Mrows, PFq, 512, 1);

    // FFN2 full-M, K=2048: y = h @ W2^T + b2 + xb, bf16 in place (1024 blocks)
    gemm_res<<<dim3(128, 8), blk, 0, stream>>>(hb, W2b, b2, nullptr, nullptr,
                                               xbuf, Mrows, 512, PFq);

    // LN2 -> out halves
    ln_b16_out<<<Mrows, blk, 0, stream>>>(xbuf, ln_g, ln_b, out);
}

// Round 2
// 319.863 us; speedup vs baseline: 1.0966x; 1.0332x over previous
//
#include <hip/hip_runtime.h>
#include <stdint.h>

// CrossAttention via linear-attention algebra, both halves merged to M=16384:
//   S = K1^T V1 + K2^T V2 (per b,h; 64x64), shared by both halves.
//   attn = Q @ S ; x = LN(inp + attn@Wo^T + bo) ; out = LN(x + FF(x))
// R10: s_kernel rewrite (latency-bound fix, 55us -> ~10us).
// R11: QKV + FFN1 moved to gemm_256 — 256x256 tile, 8-phase schedule with
// counted vmcnt(4) (never 0 in steady state), raw s_barrier, setprio around
// MFMA clusters, XCD-chunked block swizzle. Stage ledger: per iteration
// (tiles a=2I buf0 / b=2I+1 buf1): p0 b.A0, p1 b.A1, p2 c.B0, p3 c.B1 +
// vmcnt(4), p4 c.A0, p5 c.A1, p6 d.B0, p7 d.B1 + vmcnt(4). B of a tile dies
// after its phase 0 (all B-frags reg-loaded), A after phase 3 — every stage
// slot is >= its region's death barrier. Tail iteration peeled, vmcnt(0).

#define Bq 4
#define Lq 2048
#define Dq 512
#define PFq 2048
#define Mrows 16384
#define MiBu 1048576ull
#define NSLICE 16

typedef __attribute__((ext_vector_type(8))) short frag_ab;
typedef __attribute__((ext_vector_type(4))) float frag_cd;
typedef __attribute__((ext_vector_type(8))) unsigned short ushort8v;

__device__ __forceinline__ unsigned short f2b(float f) {
    union { float f; uint32_t u; } x; x.f = f;
    uint32_t r = x.u + 0x7fffu + ((x.u >> 16) & 1u);
    return (unsigned short)(r >> 16);
}
__device__ __forceinline__ float b2f(unsigned short u) {
    union { uint32_t u; float f; } x; x.u = ((uint32_t)u) << 16;
    return x.f;
}

#define GLD16(g, l)                                                              \
    __builtin_amdgcn_global_load_lds(                                            \
        (const __attribute__((address_space(1))) void*)(const void*)(g),         \
        (__attribute__((address_space(3))) void*)(void*)(l), 16, 0, 0)

// ================== 256x256 8-phase bf16 GEMM (K=512 fixed) ==================
// outB = A[M,512]b @ W[N,512]b^T + bias (+relu). 512 threads, 8 waves (2Mx4N),
// per-wave 128x64 output. LDS 128 KiB: 2 buf x (A 256x64 + B 256x64) bf16.
// grid: 1D, (M/256)*(N/256) blocks, XCD-chunked swizzle (nwg % 8 == 0).

#define STG(BUFOFS, REGOFS, GB, ROWOFS, TILE)                                    \
    { GLD16((GB) + (size_t)(ROWOFS) * 512 + (TILE) * 64,                         \
            Sh + (BUFOFS) + (REGOFS) + ld);                                      \
      GLD16((GB) + ((size_t)(ROWOFS) + 64) * 512 + (TILE) * 64,                  \
            Sh + (BUFOFS) + (REGOFS) + ld + 4096); }

#define VMW(N) asm volatile("s_waitcnt vmcnt(" #N ")" ::: "memory")

#define PHASE(CB, M0, LOADB, STAGE_STMT, WAIT_STMT)                              \
    {                                                                            \
        frag_ab a00 = *(const frag_ab*)&Sh[(CB) + (wm + (M0)*16 + lr) * 64 + xo0];      \
        frag_ab a01 = *(const frag_ab*)&Sh[(CB) + (wm + (M0)*16 + lr) * 64 + xo1];      \
        frag_ab a10 = *(const frag_ab*)&Sh[(CB) + (wm + (M0)*16 + 16 + lr) * 64 + xo0]; \
        frag_ab a11 = *(const frag_ab*)&Sh[(CB) + (wm + (M0)*16 + 16 + lr) * 64 + xo1]; \
        if (LOADB) {                                                             \
            _Pragma("unroll")                                                    \
            for (int j = 0; j < 4; ++j) {                                        \
                bf[j][0] = *(const frag_ab*)&Sh[(CB) + 16384 + (wn + j*16 + lr)*64 + xo0]; \
                bf[j][1] = *(const frag_ab*)&Sh[(CB) + 16384 + (wn + j*16 + lr)*64 + xo1]; \
            }                                                                    \
        }                                                                        \
        STAGE_STMT;                                                              \
        WAIT_STMT;                                                               \
        __builtin_amdgcn_sched_barrier(0);                                       \
        __builtin_amdgcn_s_barrier();                                            \
        asm volatile("s_waitcnt lgkmcnt(0)" ::: "memory");                       \
        __builtin_amdgcn_sched_barrier(0);                                       \
        __builtin_amdgcn_s_setprio(1);                                           \
        _Pragma("unroll")                                                        \
        for (int j = 0; j < 4; ++j) {                                            \
            acc[(M0)][j]   = __builtin_amdgcn_mfma_f32_16x16x32_bf16(a00, bf[j][0], acc[(M0)][j], 0,0,0);   \
            acc[(M0)][j]   = __builtin_amdgcn_mfma_f32_16x16x32_bf16(a01, bf[j][1], acc[(M0)][j], 0,0,0);   \
            acc[(M0)+1][j] = __builtin_amdgcn_mfma_f32_16x16x32_bf16(a10, bf[j][0], acc[(M0)+1][j], 0,0,0); \
            acc[(M0)+1][j] = __builtin_amdgcn_mfma_f32_16x16x32_bf16(a11, bf[j][1], acc[(M0)+1][j], 0,0,0); \
        }                                                                        \
        __builtin_amdgcn_s_setprio(0);                                           \
        __builtin_amdgcn_sched_barrier(0);                                       \
        __builtin_amdgcn_s_barrier();                                            \
        __builtin_amdgcn_sched_barrier(0);                                       \
    }

__global__ __launch_bounds__(512, 2) void gemm_256(
    const unsigned short* __restrict__ A, const unsigned short* __restrict__ Wt,
    const float* __restrict__ bias, unsigned short* __restrict__ outB,
    int M, int N, int relu)
{
    __shared__ __align__(16) unsigned short Sh[65536];   // 128 KiB
    const int tid = threadIdx.x;
    const int lane = tid & 63;
    const int w = tid >> 6;              // 0..7
    const int wm = (w >> 2) * 128;       // 0 / 128
    const int wn = (w & 3) * 64;         // 0..192
    const int lr = lane & 15;
    const int quad = lane >> 4;
    const int xo0 = ((quad ^ (lr & 7)) << 3);
    const int xo1 = (((4 | quad) ^ (lr & 7)) << 3);

    // XCD-chunked swizzle (nwg divisible by 8)
    const int nwg = gridDim.x;
    const int b0 = blockIdx.x;
    const int bid = (b0 & 7) * (nwg >> 3) + (b0 >> 3);
    const int mb = M >> 8;
    const size_t bm = (size_t)(bid % mb) * 256;
    const size_t bn = (size_t)(bid / mb) * 256;

    const int ar = tid >> 3;                         // 0..63
    const int sw = ((tid & 7) ^ (ar & 7)) << 3;      // pre-swizzled k-chunk
    const unsigned short* Ag = A  + (bm + ar) * (size_t)512 + sw;
    const unsigned short* Bg = Wt + (bn + ar) * (size_t)512 + sw;
    const int ld = tid * 8;                          // LDS elem offset (16B/lane)

    frag_cd acc[8][4] = {};
    frag_ab bf[4][2];

    // prologue: 0.B0 0.B1 0.A0 0.A1 1.B0 1.B1 ; need tile0 done, 2 units newer
    STG(0,     16384, Bg, 0,   0);
    STG(0,     24576, Bg, 128, 0);
    STG(0,     0,     Ag, 0,   0);
    STG(0,     8192,  Ag, 128, 0);
    STG(32768, 16384, Bg, 0,   1);
    STG(32768, 24576, Bg, 128, 1);
    VMW(4);
    __builtin_amdgcn_sched_barrier(0);
    __builtin_amdgcn_s_barrier();
    __builtin_amdgcn_sched_barrier(0);

    for (int I = 0; I < 3; ++I) {
        const int tb = 2 * I + 1, tc = 2 * I + 2, td = 2 * I + 3;
        PHASE(0,     0, 1, STG(32768, 0,     Ag, 0,   tb), (void)0);
        PHASE(0,     2, 0, STG(32768, 8192,  Ag, 128, tb), (void)0);
        PHASE(0,     4, 0, STG(0,     16384, Bg, 0,   tc), (void)0);
        PHASE(0,     6, 0, STG(0,     24576, Bg, 128, tc), VMW(4));
        PHASE(32768, 0, 1, STG(0,     0,     Ag, 0,   tc), (void)0);
        PHASE(32768, 2, 0, STG(0,     8192,  Ag, 128, tc), (void)0);
        PHASE(32768, 4, 0, STG(32768, 16384, Bg, 0,   td), (void)0);
        PHASE(32768, 6, 0, STG(32768, 24576, Bg, 128, td), VMW(4));
    }
    // tail: tiles 6 (buf0) / 7 (buf1); no stages beyond tile 7; vmcnt(0) drain
    PHASE(0,     0, 1, STG(32768, 0,    Ag, 0,   7), (void)0);
    PHASE(0,     2, 0, STG(32768, 8192, Ag, 128, 7), (void)0);
    PHASE(0,     4, 0, (void)0, (void)0);
    PHASE(0,     6, 0, (void)0, VMW(0));
    PHASE(32768, 0, 1, (void)0, (void)0);
    PHASE(32768, 2, 0, (void)0, (void)0);
    PHASE(32768, 4, 0, (void)0, (void)0);
    PHASE(32768, 6, 0, (void)0, (void)0);

    // epilogue: wave w stages its 128x64 to Sh[w*8192], then 16B/lane stores
    float bv[4];
#pragma unroll
    for (int j = 0; j < 4; ++j) bv[j] = bias[(int)bn + wn + j * 16 + lr];
    unsigned short* Cs = Sh + w * 8192;
#pragma unroll
    for (int m = 0; m < 8; ++m)
#pragma unroll
        for (int j = 0; j < 4; ++j)
#pragma unroll
            for (int r = 0; r < 4; ++r) {
                float v = acc[m][j][r] + bv[j];
                if (relu) v = fmaxf(v, 0.f);
                Cs[(m * 16 + quad * 4 + r) * 64 + j * 16 + lr] = f2b(v);
            }
    const int rl = lane >> 3, c8 = (lane & 7) * 8;
#pragma unroll
    for (int k = 0; k < 16; ++k) {
        const int row = rl + k * 8;
        ushort8v val = *(const ushort8v*)&Cs[row * 64 + c8];
        *(ushort8v*)(outB + (size_t)(bm + wm + row) * N + bn + wn + c8) = val;
    }
}

// ---------- narrow-N residual GEMM: 128x64 tile, BK=64 -------------------------
// outB = A@W^T + bias + residual. resA/resB f32 (rows <8192 / >=8192).
// resA==null: residual = b2f(outB[idx]) (in-place). grid (M/128, N/64).
__global__ __launch_bounds__(256) void gemm_res(
    const unsigned short* __restrict__ A, const unsigned short* __restrict__ Wt,
    const float* __restrict__ bias,
    const float* __restrict__ resA, const float* __restrict__ resB,
    unsigned short* __restrict__ outB, int M, int N, int K)
{
    __shared__ __align__(16) unsigned short Sh[128 * 64 + 64 * 64];
    unsigned short* At = Sh;
    unsigned short* Bt = Sh + 128 * 64;
    const int tid = threadIdx.x;
    const int lane = tid & 63;
    const int w = tid >> 6;
    const int wm = w * 32;
    const int lr = lane & 15;
    const int quad = lane >> 4;
    const size_t bm = (size_t)blockIdx.x * 128, bn = (size_t)blockIdx.y * 64;

    frag_cd acc[2][4] = {};

    const int ar = tid >> 3;
    const int acs = (((tid & 7) ^ (ar & 7)) << 3);
    const unsigned short* Ag = A  + (bm + ar) * (size_t)K + acs;
    const unsigned short* Bg = Wt + (bn + ar) * (size_t)K + acs;
    unsigned short* Asd = At + w * 512;
    unsigned short* Bsd = Bt + w * 512;

    for (int k0 = 0; k0 < K; k0 += 64) {
        __syncthreads();
#pragma unroll
        for (int i = 0; i < 4; ++i)
            GLD16(Ag + (size_t)(32 * i) * K + k0, Asd + i * 2048);
#pragma unroll
        for (int i = 0; i < 2; ++i)
            GLD16(Bg + (size_t)(32 * i) * K + k0, Bsd + i * 2048);
        __syncthreads();
#pragma unroll
        for (int kk = 0; kk < 2; ++kk) {
            frag_ab a[2], b[4];
#pragma unroll
            for (int i = 0; i < 2; ++i)
                a[i] = *(const frag_ab*)&At[(wm + i * 16 + lr) * 64 +
                                            ((((kk << 2) | quad) ^ (lr & 7)) << 3)];
#pragma unroll
            for (int j = 0; j < 4; ++j)
                b[j] = *(const frag_ab*)&Bt[(j * 16 + lr) * 64 +
                                            ((((kk << 2) | quad) ^ (lr & 7)) << 3)];
#pragma unroll
            for (int i = 0; i < 2; ++i)
#pragma unroll
                for (int j = 0; j < 4; ++j)
                    acc[i][j] = __builtin_amdgcn_mfma_f32_16x16x32_bf16(a[i], b[j], acc[i][j], 0, 0, 0);
        }
    }

    // LDS-staged epilogue: wave w owns Sh[w*2048 .. +2048) = 32x64 bf16
    __syncthreads();
    unsigned short* Cs = Sh + w * 2048;
#pragma unroll
    for (int j = 0; j < 4; ++j) {
        const float bv = bias[(int)bn + j * 16 + lr];
#pragma unroll
        for (int i = 0; i < 2; ++i)
#pragma unroll
            for (int r = 0; r < 4; ++r)
                Cs[(i * 16 + quad * 4 + r) * 64 + j * 16 + lr] = f2b(acc[i][j][r] + bv);
    }
    const int rl = lane >> 3;
    const int c8 = (lane & 7) * 8;
#pragma unroll
    for (int k = 0; k < 4; ++k) {
        const int row = rl + k * 8;
        const int grow = (int)bm + wm + row;
        const size_t idx = (size_t)grow * N + bn + c8;
        ushort8v val = *(const ushort8v*)&Cs[row * 64 + c8];
        float vv[8];
#pragma unroll
        for (int t = 0; t < 8; ++t) vv[t] = b2f(val[t]);
        if (resA) {
            const float* rp = (grow < 8192) ? resA + idx : resB + idx - (size_t)8192 * N;
            float4 ra = *(const float4*)(rp);
            float4 rb = *(const float4*)(rp + 4);
            vv[0] += ra.x; vv[1] += ra.y; vv[2] += ra.z; vv[3] += ra.w;
            vv[4] += rb.x; vv[5] += rb.y; vv[6] += rb.z; vv[7] += rb.w;
        } else {
            ushort8v old = *(const ushort8v*)(outB + idx);
#pragma unroll
            for (int t = 0; t < 8; ++t) vv[t] += b2f(old[t]);
        }
        ushort8v o;
#pragma unroll
        for (int t = 0; t < 8; ++t) o[t] = f2b(vv[t]);
        *(ushort8v*)(outB + idx) = o;
    }
}

// -------- merged fp32->bf16 converts + QKV bias concat --------
__global__ __launch_bounds__(256) void convert_all(
    const float* __restrict__ Wq, const float* __restrict__ Wk,
    const float* __restrict__ Wv, const float* __restrict__ Wo,
    const float* __restrict__ W1, const float* __restrict__ W2,
    const float* __restrict__ question, const float* __restrict__ query,
    const float* __restrict__ bqp, const float* __restrict__ bkp,
    const float* __restrict__ bvp,
    unsigned short* __restrict__ Wqkvb, unsigned short* __restrict__ Wob,
    unsigned short* __restrict__ W1b, unsigned short* __restrict__ W2b,
    unsigned short* __restrict__ Xb, float* __restrict__ bqkv)
{
    const int b = blockIdx.x;
    const float* src; unsigned short* dst; size_t off;
    if (b < 256)        { src = Wq; dst = Wqkvb;          off = (size_t)b * 1024; }
    else if (b < 512)   { src = Wk; dst = Wqkvb + 262144; off = (size_t)(b - 256) * 1024; }
    else if (b < 768)   { src = Wv; dst = Wqkvb + 524288; off = (size_t)(b - 512) * 1024; }
    else if (b < 1024)  { src = Wo; dst = Wob;            off = (size_t)(b - 768) * 1024; }
    else if (b < 2048)  { src = W1; dst = W1b;            off = (size_t)(b - 1024) * 1024; }
    else if (b < 3072)  { src = W2; dst = W2b;            off = (size_t)(b - 2048) * 1024; }
    else if (b < 7168)  { src = question; dst = Xb;       off = (size_t)(b - 3072) * 1024; }
    else if (b < 11264) { src = query; dst = Xb + 4194304; off = (size_t)(b - 7168) * 1024; }
    else {
        const int n = (b - 11264) * 256 + threadIdx.x;   // 0..1535
        bqkv[n] = (n < 512) ? bqp[n] : (n < 1024) ? bkp[n - 512] : bvp[n - 1024];
        return;
    }
    const size_t idx = off + threadIdx.x * 4;
    float4 v = *(const float4*)(src + idx);
    ushort4 o;
    o.x = f2b(v.x); o.y = f2b(v.y); o.z = f2b(v.z); o.w = f2b(v.w);
    *(ushort4*)(dst + idx) = o;
}

// ------- Spart[bh][slice] = sum over 256 l-rows of K^T outer V (merged QKV) ----
// grid (32 bh, NSLICE); 64-row fp32 LDS tiles, ushort8 loads, no atomics.
__global__ __launch_bounds__(256) void s_kernel(
    const unsigned short* __restrict__ QKV, float* __restrict__ Spart)
{
    const int bh = blockIdx.x;           // 0..31
    const int sl = blockIdx.y;           // 0..NSLICE-1
    const int b = bh >> 3, h = bh & 7;
    const int pass = sl >> 3;            // 0: question half, 1: query half
    const int l0 = (sl & 7) * 256;       // row offset within the half
    __shared__ float Ks[64][64];
    __shared__ float Vs[64][64];
    const int tid = threadIdx.x;
    const int tx = tid & 15, ty = tid >> 4;
    const int srow = tid >> 3;           // 0..31
    const int scol = (tid & 7) * 8;      // 0..56
    const size_t rowbase = (size_t)pass * 8192 + (size_t)b * Lq + l0;

    float acc[4][4] = {};

    for (int t0 = 0; t0 < 256; t0 += 64) {
        const unsigned short* kp0 = QKV + (rowbase + t0 + srow) * 1536 + 512 + h * 64 + scol;
        const unsigned short* kp1 = kp0 + (size_t)32 * 1536;
        ushort8v k0 = *(const ushort8v*)kp0;
        ushort8v v0 = *(const ushort8v*)(kp0 + 512);
        ushort8v k1 = *(const ushort8v*)kp1;
        ushort8v v1 = *(const ushort8v*)(kp1 + 512);
        __syncthreads();
#pragma unroll
        for (int e = 0; e < 8; ++e) {
            Ks[srow][scol + e]      = b2f(k0[e]);
            Vs[srow][scol + e]      = b2f(v0[e]);
            Ks[srow + 32][scol + e] = b2f(k1[e]);
            Vs[srow + 32][scol + e] = b2f(v1[e]);
        }
        __syncthreads();
#pragma unroll 4
        for (int rr = 0; rr < 64; ++rr) {
            const float4 kf = *(const float4*)&Ks[rr][ty * 4];
            const float4 vf = *(const float4*)&Vs[rr][tx * 4];
            acc[0][0] = fmaf(kf.x, vf.x, acc[0][0]);
            acc[0][1] = fmaf(kf.x, vf.y, acc[0][1]);
            acc[0][2] = fmaf(kf.x, vf.z, acc[0][2]);
            acc[0][3] = fmaf(kf.x, vf.w, acc[0][3]);
            acc[1][0] = fmaf(kf.y, vf.x, acc[1][0]);
            acc[1][1] = fmaf(kf.y, vf.y, acc[1][1]);
            acc[1][2] = fmaf(kf.y, vf.z, acc[1][2]);
            acc[1][3] = fmaf(kf.y, vf.w, acc[1][3]);
            acc[2][0] = fmaf(kf.z, vf.x, acc[2][0]);
            acc[2][1] = fmaf(kf.z, vf.y, acc[2][1]);
            acc[2][2] = fmaf(kf.z, vf.z, acc[2][2]);
            acc[2][3] = fmaf(kf.z, vf.w, acc[2][3]);
            acc[3][0] = fmaf(kf.w, vf.x, acc[3][0]);
            acc[3][1] = fmaf(kf.w, vf.y, acc[3][1]);
            acc[3][2] = fmaf(kf.w, vf.z, acc[3][2]);
            acc[3][3] = fmaf(kf.w, vf.w, acc[3][3]);
        }
    }

    float* Sp = Spart + ((size_t)bh * NSLICE + sl) * 4096;
#pragma unroll
    for (int i = 0; i < 4; ++i) {
        float4 o = make_float4(acc[i][0], acc[i][1], acc[i][2], acc[i][3]);
        *(float4*)(Sp + (ty * 4 + i) * 64 + tx * 4) = o;
    }
}

// ------- reduce NSLICE partials -> Sbt bf16, B-layout [bh][khalf][n][kj] -------
// grid (32, 4)
__global__ __launch_bounds__(256) void sbt_convert(
    const float* __restrict__ Spart, unsigned short* __restrict__ Sbt)
{
    const int bh = blockIdx.x;
    const int uo = blockIdx.y;           // 0..3
    const float* Sp = Spart + (size_t)bh * (NSLICE * 4096);
    unsigned short* Dp = Sbt + (size_t)bh * 4096;
    const int t = threadIdx.x;
#pragma unroll
    for (int u = 0; u < 4; ++u) {
        const int d = (uo * 4 + u) * 256 + t;    // element of row-major S[64][64]
        float v = 0.f;
#pragma unroll
        for (int s = 0; s < NSLICE; ++s) v += Sp[(size_t)s * 4096 + d];
        const int row = d >> 6, col = d & 63;    // row = dk, col = n
        Dp[(row >> 5) * 2048 + col * 32 + (row & 31)] = f2b(v);
    }
}

// ------- attn = Q @ S_bh via MFMA; block: 128 rows x 64 cols (one head) -------
__global__ __launch_bounds__(256) void attn_mfma(
    const unsigned short* __restrict__ QKV, const unsigned short* __restrict__ Sbt,
    unsigned short* __restrict__ Ob)
{
    __shared__ __align__(16) unsigned short Sh[2 * 128 * 32 + 2 * 64 * 32];
    unsigned short* At = Sh;
    unsigned short* Bt = Sh + 2 * 128 * 32;
    const int h = blockIdx.x;
    const int rbase = blockIdx.y * 128;
    const int b = (rbase >> 11) & 3;
    const int bh = b * 8 + h;
    const int tid = threadIdx.x;
    const int lane = tid & 63;
    const int w = tid >> 6;
    const int lr = lane & 15;
    const int quad = lane >> 4;

    {
        const int rloc = tid >> 2, c8 = (tid & 3) * 8;
#pragma unroll
        for (int it = 0; it < 4; ++it) {
            const int kk = it & 1, rh = it >> 1;
            const unsigned short* g = QKV +
                ((size_t)rbase + rh * 64 + rloc) * 1536 + h * 64 + kk * 32 + c8;
            GLD16(g, At + kk * 4096 + rh * 2048 + w * 512);
        }
        const unsigned short* Sg = Sbt + (size_t)bh * 4096 + tid * 8;
#pragma unroll
        for (int bi = 0; bi < 2; ++bi)
            GLD16(Sg + bi * 2048, Bt + bi * 2048 + w * 512);
    }
    __syncthreads();

    frag_cd acc[2][4] = {};
#pragma unroll
    for (int kk = 0; kk < 2; ++kk) {
        frag_ab a[2], bfr[4];
#pragma unroll
        for (int i = 0; i < 2; ++i)
            a[i] = *(const frag_ab*)&At[kk * 4096 + (w * 32 + i * 16 + lr) * 32 + quad * 8];
#pragma unroll
        for (int j = 0; j < 4; ++j)
            bfr[j] = *(const frag_ab*)&Bt[kk * 2048 + (j * 16 + lr) * 32 + quad * 8];
#pragma unroll
        for (int i = 0; i < 2; ++i)
#pragma unroll
            for (int j = 0; j < 4; ++j)
                acc[i][j] = __builtin_amdgcn_mfma_f32_16x16x32_bf16(a[i], bfr[j], acc[i][j], 0, 0, 0);
    }

    __syncthreads();
    unsigned short* Cs = Sh + w * 2048;
#pragma unroll
    for (int i = 0; i < 2; ++i)
#pragma unroll
        for (int j = 0; j < 4; ++j)
#pragma unroll
            for (int r = 0; r < 4; ++r)
                Cs[(i * 16 + quad * 4 + r) * 64 + j * 16 + lr] = f2b(acc[i][j][r]);
    const int rl = lane >> 3;
    const int c8o = (lane & 7) * 8;
#pragma unroll
    for (int k = 0; k < 4; ++k) {
        const int row = rl + k * 8;
        ushort8v val = *(const ushort8v*)&Cs[row * 64 + c8o];
        *(ushort8v*)(Ob + (size_t)(rbase + w * 32 + row) * 512 + h * 64 + c8o) = val;
    }
}

// ------- LN over bf16 row (512) in place; wave-shuffle reduction -------
__global__ __launch_bounds__(256) void ln_b16_inplace(
    unsigned short* __restrict__ Y, const float* __restrict__ g,
    const float* __restrict__ bta)
{
    __shared__ float part[8];
    const int row = blockIdx.x;
    const int t = threadIdx.x;
    const int w = t >> 6;
    unsigned short* yr = Y + (size_t)row * Dq;
    const float v0 = b2f(yr[t]), v1 = b2f(yr[t + 256]);
    float s = v0 + v1;
#pragma unroll
    for (int off = 32; off; off >>= 1) s += __shfl_xor(s, off, 64);
    if ((t & 63) == 0) part[w] = s;
    __syncthreads();
    const float mean = (part[0] + part[1] + part[2] + part[3]) * (1.f / Dq);
    const float d0 = v0 - mean, d1 = v1 - mean;
    float q = d0 * d0 + d1 * d1;
#pragma unroll
    for (int off = 32; off; off >>= 1) q += __shfl_xor(q, off, 64);
    if ((t & 63) == 0) part[4 + w] = q;
    __syncthreads();
    const float rstd = rsqrtf((part[4] + part[5] + part[6] + part[7]) * (1.f / Dq) + 1e-5f);
    yr[t] = f2b(d0 * rstd * g[t] + bta[t]);
    yr[t + 256] = f2b(d1 * rstd * g[t + 256] + bta[t + 256]);
}

// ------- LN over bf16 row -> out f32 half-columns (merged rows) -------
__global__ __launch_bounds__(256) void ln_b16_out(
    const unsigned short* __restrict__ Y, const float* __restrict__ g,
    const float* __restrict__ bta, float* __restrict__ out)
{
    __shared__ float part[8];
    const int row = blockIdx.x;
    const int t = threadIdx.x;
    const int w = t >> 6;
    const unsigned short* yr = Y + (size_t)row * Dq;
    const float v0 = b2f(yr[t]), v1 = b2f(yr[t + 256]);
    float s = v0 + v1;
#pragma unroll
    for (int off = 32; off; off >>= 1) s += __shfl_xor(s, off, 64);
    if ((t & 63) == 0) part[w] = s;
    __syncthreads();
    const float mean = (part[0] + part[1] + part[2] + part[3]) * (1.f / Dq);
    const float d0 = v0 - mean, d1 = v1 - mean;
    float q = d0 * d0 + d1 * d1;
#pragma unroll
    for (int off = 32; off; off >>= 1) q += __shfl_xor(q, off, 64);
    if ((t & 63) == 0) part[4 + w] = q;
    __syncthreads();
    const float rstd = rsqrtf((part[4] + part[5] + part[6] + part[7]) * (1.f / Dq) + 1e-5f);
    const int half = row >> 13, br = row & 8191;
    float* orow = out + (size_t)br * 1024 + half * 512;
    orow[t] = d0 * rstd * g[t] + bta[t];
    orow[t + 256] = d1 * rstd * g[t + 256] + bta[t + 256];
}

extern "C" void kernel_launch(void* const* d_in, const int* in_sizes, int n_in,
                              void* d_out, int out_size, void* d_ws, size_t ws_size,
                              hipStream_t stream)
{
    const float* question = (const float*)d_in[0];
    const float* query    = (const float*)d_in[1];
    const float* Wq = (const float*)d_in[2];  const float* bqp = (const float*)d_in[3];
    const float* Wk = (const float*)d_in[4];  const float* bkp = (const float*)d_in[5];
    const float* Wv = (const float*)d_in[6];  const float* bvp = (const float*)d_in[7];
    const float* Wo = (const float*)d_in[8];  const float* bo  = (const float*)d_in[9];
    const float* ln_g = (const float*)d_in[10]; const float* ln_b = (const float*)d_in[11];
    const float* W1 = (const float*)d_in[12]; const float* b1 = (const float*)d_in[13];
    const float* W2 = (const float*)d_in[14]; const float* b2 = (const float*)d_in[15];
    float* out = (float*)d_out;
    char* ws = (char*)d_ws;

    // ---- workspace (~87 MiB) ----
    unsigned short* QKVb  = (unsigned short*)(ws);
    unsigned short* attnb = (unsigned short*)(ws + 48 * MiBu);
    float* Spart          = (float*)(ws + 48 * MiBu);           // dead before attnb
    unsigned short* Xb    = (unsigned short*)(ws + 64 * MiBu);
    unsigned short* xbuf  = (unsigned short*)(ws + 64 * MiBu);  // y0b -> xb -> y
    unsigned short* hb    = (unsigned short*)(ws);              // [16384,2048] bf16
    char* wp = ws + 80 * MiBu + 524288;
    unsigned short* Wqkvb = (unsigned short*)wp;  wp += 1536 * 512 * 2;
    unsigned short* Wob   = (unsigned short*)wp;  wp += 512 * 512 * 2;
    unsigned short* W1b   = (unsigned short*)wp;  wp += 2048 * 512 * 2;
    unsigned short* W2b   = (unsigned short*)wp;  wp += 512 * 2048 * 2;
    unsigned short* Sbt   = (unsigned short*)wp;  wp += 32 * 4096 * 2;
    float* bqkv           = (float*)wp;

    dim3 blk(256);

    convert_all<<<11270, blk, 0, stream>>>(Wq, Wk, Wv, Wo, W1, W2, question, query,
                                           bqp, bkp, bvp,
                                           Wqkvb, Wob, W1b, W2b, Xb, bqkv);

    // QKV: [16384,512]@[1536,512]^T -> bf16 (256^2 8-phase; 384 blocks)
    gemm_256<<<dim3(384), dim3(512), 0, stream>>>(Xb, Wqkvb, bqkv, QKVb,
                                                  Mrows, 1536, 0);

    // S partials (fp32, no atomics) -> reduce+pack bf16 B-layout; attn via MFMA
    s_kernel<<<dim3(32, NSLICE), blk, 0, stream>>>(QKVb, Spart);
    sbt_convert<<<dim3(32, 4), blk, 0, stream>>>(Spart, Sbt);
    attn_mfma<<<dim3(8, 128), blk, 0, stream>>>(QKVb, Sbt, attnb);

    // o-proj + residual(inputs) + bo -> bf16 y0b (128x64 tiles, 1024 blocks)
    gemm_res<<<dim3(128, 8), blk, 0, stream>>>(attnb, Wob, bo, question, query,
                                               xbuf, Mrows, 512, 512);

    // LN1 in place: xb = LN(y0b)
    ln_b16_inplace<<<Mrows, blk, 0, stream>>>(xbuf, ln_g, ln_b);

    // FFN1 full-M: h = relu(xb @ W1^T + b1) -> bf16 [16384,2048] (256^2 8-phase)
    gemm_256<<<dim3(512), dim3(512), 0, stream>>>(xbuf, W1b, b1, hb,
                                                  Mrows, PFq, 1);

    // FFN2 full-M, K=2048: y = h @ W2^T + b2 + xb, bf16 in place (1024 blocks)
    gemm_res<<<dim3(128, 8), blk, 0, stream>>>(hb, W2b, b2, nullptr, nullptr,
                                               xbuf, Mrows, 512, PFq);

    // LN2 -> out halves
    ln_b16_out<<<Mrows, blk, 0, stream>>>(xbuf, ln_g, ln_b, out);
}

// Round 3
// 317.849 us; speedup vs baseline: 1.1036x; 1.0063x over previous
//
#include <hip/hip_runtime.h>
#include <stdint.h>

// CrossAttention via linear-attention algebra, both halves merged to M=16384:
//   S = K1^T V1 + K2^T V2 (per b,h; 64x64), shared by both halves.
//   attn = Q @ S ; x = LN(inp + attn@Wo^T + bo) ; out = LN(x + FF(x))
// R10: s_kernel rewrite (latency-bound fix, 55us -> ~10us).
// R11: QKV + FFN1 on gemm_256 (256x256 8-phase, counted vmcnt).
// R12: o-proj + FFN2 moved off the serial 128x64 gemm_res onto gemm_res256:
// 256x128 tile (grid 64x4 = 256 blocks = full GPU at 1 block/CU), 4-phase
// schedule, 16 MFMA/phase, counted vmcnt(2) (never 0 in steady state).
// Ledger (tiles a=2I buf0, b=2I+1 buf1; stage c=2I+2 buf0, d=2I+3 buf1):
//   P0 bA0,bA1 | P1 cB + vmcnt(2) | P2 cA0,cA1 | P3 dB + vmcnt(2)
// Region deaths: buf.B after its LOADB phase, buf.A after its 2nd M-phase —
// every stage slot >= death barrier. FFN2 K=2048 -> 16 iters (deep pipeline).

#define Bq 4
#define Lq 2048
#define Dq 512
#define PFq 2048
#define Mrows 16384
#define MiBu 1048576ull
#define NSLICE 16

typedef __attribute__((ext_vector_type(8))) short frag_ab;
typedef __attribute__((ext_vector_type(4))) float frag_cd;
typedef __attribute__((ext_vector_type(8))) unsigned short ushort8v;

__device__ __forceinline__ unsigned short f2b(float f) {
    union { float f; uint32_t u; } x; x.f = f;
    uint32_t r = x.u + 0x7fffu + ((x.u >> 16) & 1u);
    return (unsigned short)(r >> 16);
}
__device__ __forceinline__ float b2f(unsigned short u) {
    union { uint32_t u; float f; } x; x.u = ((uint32_t)u) << 16;
    return x.f;
}

#define GLD16(g, l)                                                              \
    __builtin_amdgcn_global_load_lds(                                            \
        (const __attribute__((address_space(1))) void*)(const void*)(g),         \
        (__attribute__((address_space(3))) void*)(void*)(l), 16, 0, 0)

// One stage unit: 128 rows x 64 k-cols bf16 (2x global_load_lds_dwordx4/thread)
#define STG(BUFOFS, REGOFS, GB, ROWOFS, TILE, KS)                                \
    { GLD16((GB) + (size_t)(ROWOFS) * (KS) + (TILE) * 64,                        \
            Sh + (BUFOFS) + (REGOFS) + ld);                                      \
      GLD16((GB) + ((size_t)(ROWOFS) + 64) * (KS) + (TILE) * 64,                 \
            Sh + (BUFOFS) + (REGOFS) + ld + 4096); }

#define VMW(N) asm volatile("s_waitcnt vmcnt(" #N ")" ::: "memory")

// One phase: ds-read 2 M-frags (+8 B-frags if LOADB), issue stages, counted
// wait, barrier, 16 MFMA under setprio, barrier. A region = 16384 elems.
#define PHASE(CB, M0, LOADB, STAGE_STMT, WAIT_STMT)                              \
    {                                                                            \
        frag_ab a00 = *(const frag_ab*)&Sh[(CB) + (wm + (M0)*16 + lr) * 64 + xo0];      \
        frag_ab a01 = *(const frag_ab*)&Sh[(CB) + (wm + (M0)*16 + lr) * 64 + xo1];      \
        frag_ab a10 = *(const frag_ab*)&Sh[(CB) + (wm + (M0)*16 + 16 + lr) * 64 + xo0]; \
        frag_ab a11 = *(const frag_ab*)&Sh[(CB) + (wm + (M0)*16 + 16 + lr) * 64 + xo1]; \
        if (LOADB) {                                                             \
            _Pragma("unroll")                                                    \
            for (int j = 0; j < 4; ++j) {                                        \
                bf[j][0] = *(const frag_ab*)&Sh[(CB) + 16384 + (wn + j*16 + lr)*64 + xo0]; \
                bf[j][1] = *(const frag_ab*)&Sh[(CB) + 16384 + (wn + j*16 + lr)*64 + xo1]; \
            }                                                                    \
        }                                                                        \
        STAGE_STMT;                                                              \
        WAIT_STMT;                                                               \
        __builtin_amdgcn_sched_barrier(0);                                       \
        __builtin_amdgcn_s_barrier();                                            \
        asm volatile("s_waitcnt lgkmcnt(0)" ::: "memory");                       \
        __builtin_amdgcn_sched_barrier(0);                                       \
        __builtin_amdgcn_s_setprio(1);                                           \
        _Pragma("unroll")                                                        \
        for (int j = 0; j < 4; ++j) {                                            \
            acc[(M0)][j]   = __builtin_amdgcn_mfma_f32_16x16x32_bf16(a00, bf[j][0], acc[(M0)][j], 0,0,0);   \
            acc[(M0)][j]   = __builtin_amdgcn_mfma_f32_16x16x32_bf16(a01, bf[j][1], acc[(M0)][j], 0,0,0);   \
            acc[(M0)+1][j] = __builtin_amdgcn_mfma_f32_16x16x32_bf16(a10, bf[j][0], acc[(M0)+1][j], 0,0,0); \
            acc[(M0)+1][j] = __builtin_amdgcn_mfma_f32_16x16x32_bf16(a11, bf[j][1], acc[(M0)+1][j], 0,0,0); \
        }                                                                        \
        __builtin_amdgcn_s_setprio(0);                                           \
        __builtin_amdgcn_sched_barrier(0);                                       \
        __builtin_amdgcn_s_barrier();                                            \
        __builtin_amdgcn_sched_barrier(0);                                       \
    }

// ================== 256x256 8-phase bf16 GEMM (K=512 fixed) ==================
// outB = A[M,512]b @ W[N,512]b^T + bias (+relu). 512 threads, 8 waves (2Mx4N),
// per-wave 128x64 output. LDS 128 KiB: 2 buf x (A 256x64 + B 256x64) bf16.
// grid: 1D, (M/256)*(N/256) blocks, XCD-chunked swizzle (nwg % 8 == 0).
__global__ __launch_bounds__(512, 2) void gemm_256(
    const unsigned short* __restrict__ A, const unsigned short* __restrict__ Wt,
    const float* __restrict__ bias, unsigned short* __restrict__ outB,
    int M, int N, int relu)
{
    __shared__ __align__(16) unsigned short Sh[65536];   // 128 KiB
    const int tid = threadIdx.x;
    const int lane = tid & 63;
    const int w = tid >> 6;              // 0..7
    const int wm = (w >> 2) * 128;       // 0 / 128
    const int wn = (w & 3) * 64;         // 0..192
    const int lr = lane & 15;
    const int quad = lane >> 4;
    const int xo0 = ((quad ^ (lr & 7)) << 3);
    const int xo1 = (((4 | quad) ^ (lr & 7)) << 3);

    const int nwg = gridDim.x;
    const int b0 = blockIdx.x;
    const int bid = (b0 & 7) * (nwg >> 3) + (b0 >> 3);
    const int mb = M >> 8;
    const size_t bm = (size_t)(bid % mb) * 256;
    const size_t bn = (size_t)(bid / mb) * 256;

    const int ar = tid >> 3;                         // 0..63
    const int sw = ((tid & 7) ^ (ar & 7)) << 3;      // pre-swizzled k-chunk
    const unsigned short* Ag = A  + (bm + ar) * (size_t)512 + sw;
    const unsigned short* Bg = Wt + (bn + ar) * (size_t)512 + sw;
    const int ld = tid * 8;                          // LDS elem offset (16B/lane)

    frag_cd acc[8][4] = {};
    frag_ab bf[4][2];

    // prologue: 0.B0 0.B1 0.A0 0.A1 1.B0 1.B1
    STG(0,     16384, Bg, 0,   0, 512);
    STG(0,     24576, Bg, 128, 0, 512);
    STG(0,     0,     Ag, 0,   0, 512);
    STG(0,     8192,  Ag, 128, 0, 512);
    STG(32768, 16384, Bg, 0,   1, 512);
    STG(32768, 24576, Bg, 128, 1, 512);
    VMW(4);
    __builtin_amdgcn_sched_barrier(0);
    __builtin_amdgcn_s_barrier();
    __builtin_amdgcn_sched_barrier(0);

    for (int I = 0; I < 3; ++I) {
        const int tb = 2 * I + 1, tc = 2 * I + 2, td = 2 * I + 3;
        PHASE(0,     0, 1, STG(32768, 0,     Ag, 0,   tb, 512), (void)0);
        PHASE(0,     2, 0, STG(32768, 8192,  Ag, 128, tb, 512), (void)0);
        PHASE(0,     4, 0, STG(0,     16384, Bg, 0,   tc, 512), (void)0);
        PHASE(0,     6, 0, STG(0,     24576, Bg, 128, tc, 512), VMW(4));
        PHASE(32768, 0, 1, STG(0,     0,     Ag, 0,   tc, 512), (void)0);
        PHASE(32768, 2, 0, STG(0,     8192,  Ag, 128, tc, 512), (void)0);
        PHASE(32768, 4, 0, STG(32768, 16384, Bg, 0,   td, 512), (void)0);
        PHASE(32768, 6, 0, STG(32768, 24576, Bg, 128, td, 512), VMW(4));
    }
    PHASE(0,     0, 1, STG(32768, 0,    Ag, 0,   7, 512), (void)0);
    PHASE(0,     2, 0, STG(32768, 8192, Ag, 128, 7, 512), (void)0);
    PHASE(0,     4, 0, (void)0, (void)0);
    PHASE(0,     6, 0, (void)0, VMW(0));
    PHASE(32768, 0, 1, (void)0, (void)0);
    PHASE(32768, 2, 0, (void)0, (void)0);
    PHASE(32768, 4, 0, (void)0, (void)0);
    PHASE(32768, 6, 0, (void)0, (void)0);

    // epilogue: wave w stages its 128x64 to Sh[w*8192], then 16B/lane stores
    float bv[4];
#pragma unroll
    for (int j = 0; j < 4; ++j) bv[j] = bias[(int)bn + wn + j * 16 + lr];
    unsigned short* Cs = Sh + w * 8192;
#pragma unroll
    for (int m = 0; m < 8; ++m)
#pragma unroll
        for (int j = 0; j < 4; ++j)
#pragma unroll
            for (int r = 0; r < 4; ++r) {
                float v = acc[m][j][r] + bv[j];
                if (relu) v = fmaxf(v, 0.f);
                Cs[(m * 16 + quad * 4 + r) * 64 + j * 16 + lr] = f2b(v);
            }
    const int rl = lane >> 3, c8 = (lane & 7) * 8;
#pragma unroll
    for (int k = 0; k < 16; ++k) {
        const int row = rl + k * 8;
        ushort8v val = *(const ushort8v*)&Cs[row * 64 + c8];
        *(ushort8v*)(outB + (size_t)(bm + wm + row) * N + bn + wn + c8) = val;
    }
}

// ========== 256x128 4-phase residual GEMM, N=512 fixed, runtime K ============
// outB = A@W^T + bias + residual. resA/resB f32 (rows <8192 / >=8192);
// resA==null: residual = b2f(outB[idx]) (in-place). grid 256 blocks, 512 thr.
// LDS 96 KiB: 2 buf x (A 256x64 = 32K + B 128x64 = 16K). 8 waves 4Mx2N,
// per-wave 64x64 (acc[4][4]).
__global__ __launch_bounds__(512, 2) void gemm_res256(
    const unsigned short* __restrict__ A, const unsigned short* __restrict__ Wt,
    const float* __restrict__ bias,
    const float* __restrict__ resA, const float* __restrict__ resB,
    unsigned short* __restrict__ outB, int K)
{
    __shared__ __align__(16) unsigned short Sh[49152];   // 96 KiB
    const int tid = threadIdx.x;
    const int lane = tid & 63;
    const int w = tid >> 6;              // 0..7
    const int wm = (w >> 1) * 64;        // 0/64/128/192
    const int wn = (w & 1) * 64;         // 0/64
    const int lr = lane & 15;
    const int quad = lane >> 4;
    const int xo0 = ((quad ^ (lr & 7)) << 3);
    const int xo1 = (((4 | quad) ^ (lr & 7)) << 3);

    // XCD-chunked swizzle; nwg = 256
    const int b0 = blockIdx.x;
    const int bid = (b0 & 7) * 32 + (b0 >> 3);
    const size_t bm = (size_t)(bid & 63) * 256;
    const size_t bn = (size_t)(bid >> 6) * 128;

    const int ar = tid >> 3;
    const int sw = ((tid & 7) ^ (ar & 7)) << 3;
    const unsigned short* Ag = A  + (bm + ar) * (size_t)K + sw;
    const unsigned short* Bg = Wt + (bn + ar) * (size_t)K + sw;
    const int ld = tid * 8;

    frag_cd acc[4][4] = {};
    frag_ab bf[4][2];

    // prologue: aB aA0 aA1 bB ; wait all but bB
    STG(0,     16384, Bg, 0,   0, K);
    STG(0,     0,     Ag, 0,   0, K);
    STG(0,     8192,  Ag, 128, 0, K);
    STG(24576, 16384, Bg, 0,   1, K);
    VMW(2);
    __builtin_amdgcn_sched_barrier(0);
    __builtin_amdgcn_s_barrier();
    __builtin_amdgcn_sched_barrier(0);

    const int nIter = K >> 7;            // 2 K-tiles per iteration
    for (int I = 0; I < nIter - 1; ++I) {
        const int tb = 2 * I + 1, tc = 2 * I + 2, td = 2 * I + 3;
        PHASE(0,     0, 1, { STG(24576, 0, Ag, 0, tb, K); STG(24576, 8192, Ag, 128, tb, K); }, (void)0);
        PHASE(0,     2, 0, STG(0, 16384, Bg, 0, tc, K), VMW(2));
        PHASE(24576, 0, 1, { STG(0, 0, Ag, 0, tc, K); STG(0, 8192, Ag, 128, tc, K); }, (void)0);
        PHASE(24576, 2, 0, STG(24576, 16384, Bg, 0, td, K), VMW(2));
    }
    {   // tail: computes tiles 2(nIter-1), 2nIter-1; only b's A left to stage
        const int tb = (K >> 6) - 1;
        PHASE(0,     0, 1, { STG(24576, 0, Ag, 0, tb, K); STG(24576, 8192, Ag, 128, tb, K); }, (void)0);
        PHASE(0,     2, 0, (void)0, VMW(0));
        PHASE(24576, 0, 1, (void)0, (void)0);
        PHASE(24576, 2, 0, (void)0, (void)0);
    }

    // epilogue: wave w stages its 64x64 to Sh[w*4096]; residual added post-LDS
    float bv[4];
#pragma unroll
    for (int j = 0; j < 4; ++j) bv[j] = bias[(int)bn + wn + j * 16 + lr];
    unsigned short* Cs = Sh + w * 4096;
#pragma unroll
    for (int m = 0; m < 4; ++m)
#pragma unroll
        for (int j = 0; j < 4; ++j)
#pragma unroll
            for (int r = 0; r < 4; ++r)
                Cs[(m * 16 + quad * 4 + r) * 64 + j * 16 + lr] = f2b(acc[m][j][r] + bv[j]);
    const int rl = lane >> 3, c8 = (lane & 7) * 8;
#pragma unroll
    for (int k = 0; k < 8; ++k) {
        const int row = rl + k * 8;
        const int grow = (int)bm + wm + row;
        const size_t idx = (size_t)grow * 512 + bn + wn + c8;
        ushort8v val = *(const ushort8v*)&Cs[row * 64 + c8];
        float vv[8];
#pragma unroll
        for (int t = 0; t < 8; ++t) vv[t] = b2f(val[t]);
        if (resA) {
            const float* rp = (grow < 8192) ? resA + idx : resB + idx - (size_t)8192 * 512;
            float4 ra = *(const float4*)(rp);
            float4 rb = *(const float4*)(rp + 4);
            vv[0] += ra.x; vv[1] += ra.y; vv[2] += ra.z; vv[3] += ra.w;
            vv[4] += rb.x; vv[5] += rb.y; vv[6] += rb.z; vv[7] += rb.w;
        } else {
            ushort8v old = *(const ushort8v*)(outB + idx);
#pragma unroll
            for (int t = 0; t < 8; ++t) vv[t] += b2f(old[t]);
        }
        ushort8v o;
#pragma unroll
        for (int t = 0; t < 8; ++t) o[t] = f2b(vv[t]);
        *(ushort8v*)(outB + idx) = o;
    }
}

// -------- merged fp32->bf16 converts + QKV bias concat --------
__global__ __launch_bounds__(256) void convert_all(
    const float* __restrict__ Wq, const float* __restrict__ Wk,
    const float* __restrict__ Wv, const float* __restrict__ Wo,
    const float* __restrict__ W1, const float* __restrict__ W2,
    const float* __restrict__ question, const float* __restrict__ query,
    const float* __restrict__ bqp, const float* __restrict__ bkp,
    const float* __restrict__ bvp,
    unsigned short* __restrict__ Wqkvb, unsigned short* __restrict__ Wob,
    unsigned short* __restrict__ W1b, unsigned short* __restrict__ W2b,
    unsigned short* __restrict__ Xb, float* __restrict__ bqkv)
{
    const int b = blockIdx.x;
    const float* src; unsigned short* dst; size_t off;
    if (b < 256)        { src = Wq; dst = Wqkvb;          off = (size_t)b * 1024; }
    else if (b < 512)   { src = Wk; dst = Wqkvb + 262144; off = (size_t)(b - 256) * 1024; }
    else if (b < 768)   { src = Wv; dst = Wqkvb + 524288; off = (size_t)(b - 512) * 1024; }
    else if (b < 1024)  { src = Wo; dst = Wob;            off = (size_t)(b - 768) * 1024; }
    else if (b < 2048)  { src = W1; dst = W1b;            off = (size_t)(b - 1024) * 1024; }
    else if (b < 3072)  { src = W2; dst = W2b;            off = (size_t)(b - 2048) * 1024; }
    else if (b < 7168)  { src = question; dst = Xb;       off = (size_t)(b - 3072) * 1024; }
    else if (b < 11264) { src = query; dst = Xb + 4194304; off = (size_t)(b - 7168) * 1024; }
    else {
        const int n = (b - 11264) * 256 + threadIdx.x;   // 0..1535
        bqkv[n] = (n < 512) ? bqp[n] : (n < 1024) ? bkp[n - 512] : bvp[n - 1024];
        return;
    }
    const size_t idx = off + threadIdx.x * 4;
    float4 v = *(const float4*)(src + idx);
    ushort4 o;
    o.x = f2b(v.x); o.y = f2b(v.y); o.z = f2b(v.z); o.w = f2b(v.w);
    *(ushort4*)(dst + idx) = o;
}

// ------- Spart[bh][slice] = sum over 256 l-rows of K^T outer V (merged QKV) ----
__global__ __launch_bounds__(256) void s_kernel(
    const unsigned short* __restrict__ QKV, float* __restrict__ Spart)
{
    const int bh = blockIdx.x;           // 0..31
    const int sl = blockIdx.y;           // 0..NSLICE-1
    const int b = bh >> 3, h = bh & 7;
    const int pass = sl >> 3;
    const int l0 = (sl & 7) * 256;
    __shared__ float Ks[64][64];
    __shared__ float Vs[64][64];
    const int tid = threadIdx.x;
    const int tx = tid & 15, ty = tid >> 4;
    const int srow = tid >> 3;
    const int scol = (tid & 7) * 8;
    const size_t rowbase = (size_t)pass * 8192 + (size_t)b * Lq + l0;

    float acc[4][4] = {};

    for (int t0 = 0; t0 < 256; t0 += 64) {
        const unsigned short* kp0 = QKV + (rowbase + t0 + srow) * 1536 + 512 + h * 64 + scol;
        const unsigned short* kp1 = kp0 + (size_t)32 * 1536;
        ushort8v k0 = *(const ushort8v*)kp0;
        ushort8v v0 = *(const ushort8v*)(kp0 + 512);
        ushort8v k1 = *(const ushort8v*)kp1;
        ushort8v v1 = *(const ushort8v*)(kp1 + 512);
        __syncthreads();
#pragma unroll
        for (int e = 0; e < 8; ++e) {
            Ks[srow][scol + e]      = b2f(k0[e]);
            Vs[srow][scol + e]      = b2f(v0[e]);
            Ks[srow + 32][scol + e] = b2f(k1[e]);
            Vs[srow + 32][scol + e] = b2f(v1[e]);
        }
        __syncthreads();
#pragma unroll 4
        for (int rr = 0; rr < 64; ++rr) {
            const float4 kf = *(const float4*)&Ks[rr][ty * 4];
            const float4 vf = *(const float4*)&Vs[rr][tx * 4];
            acc[0][0] = fmaf(kf.x, vf.x, acc[0][0]);
            acc[0][1] = fmaf(kf.x, vf.y, acc[0][1]);
            acc[0][2] = fmaf(kf.x, vf.z, acc[0][2]);
            acc[0][3] = fmaf(kf.x, vf.w, acc[0][3]);
            acc[1][0] = fmaf(kf.y, vf.x, acc[1][0]);
            acc[1][1] = fmaf(kf.y, vf.y, acc[1][1]);
            acc[1][2] = fmaf(kf.y, vf.z, acc[1][2]);
            acc[1][3] = fmaf(kf.y, vf.w, acc[1][3]);
            acc[2][0] = fmaf(kf.z, vf.x, acc[2][0]);
            acc[2][1] = fmaf(kf.z, vf.y, acc[2][1]);
            acc[2][2] = fmaf(kf.z, vf.z, acc[2][2]);
            acc[2][3] = fmaf(kf.z, vf.w, acc[2][3]);
            acc[3][0] = fmaf(kf.w, vf.x, acc[3][0]);
            acc[3][1] = fmaf(kf.w, vf.y, acc[3][1]);
            acc[3][2] = fmaf(kf.w, vf.z, acc[3][2]);
            acc[3][3] = fmaf(kf.w, vf.w, acc[3][3]);
        }
    }

    float* Sp = Spart + ((size_t)bh * NSLICE + sl) * 4096;
#pragma unroll
    for (int i = 0; i < 4; ++i) {
        float4 o = make_float4(acc[i][0], acc[i][1], acc[i][2], acc[i][3]);
        *(float4*)(Sp + (ty * 4 + i) * 64 + tx * 4) = o;
    }
}

// ------- reduce NSLICE partials -> Sbt bf16, B-layout [bh][khalf][n][kj] -------
__global__ __launch_bounds__(256) void sbt_convert(
    const float* __restrict__ Spart, unsigned short* __restrict__ Sbt)
{
    const int bh = blockIdx.x;
    const int uo = blockIdx.y;           // 0..3
    const float* Sp = Spart + (size_t)bh * (NSLICE * 4096);
    unsigned short* Dp = Sbt + (size_t)bh * 4096;
    const int t = threadIdx.x;
#pragma unroll
    for (int u = 0; u < 4; ++u) {
        const int d = (uo * 4 + u) * 256 + t;
        float v = 0.f;
#pragma unroll
        for (int s = 0; s < NSLICE; ++s) v += Sp[(size_t)s * 4096 + d];
        const int row = d >> 6, col = d & 63;
        Dp[(row >> 5) * 2048 + col * 32 + (row & 31)] = f2b(v);
    }
}

// ------- attn = Q @ S_bh via MFMA; block: 128 rows x 64 cols (one head) -------
__global__ __launch_bounds__(256) void attn_mfma(
    const unsigned short* __restrict__ QKV, const unsigned short* __restrict__ Sbt,
    unsigned short* __restrict__ Ob)
{
    __shared__ __align__(16) unsigned short Sh[2 * 128 * 32 + 2 * 64 * 32];
    unsigned short* At = Sh;
    unsigned short* Bt = Sh + 2 * 128 * 32;
    const int h = blockIdx.x;
    const int rbase = blockIdx.y * 128;
    const int b = (rbase >> 11) & 3;
    const int bh = b * 8 + h;
    const int tid = threadIdx.x;
    const int lane = tid & 63;
    const int w = tid >> 6;
    const int lr = lane & 15;
    const int quad = lane >> 4;

    {
        const int rloc = tid >> 2, c8 = (tid & 3) * 8;
#pragma unroll
        for (int it = 0; it < 4; ++it) {
            const int kk = it & 1, rh = it >> 1;
            const unsigned short* g = QKV +
                ((size_t)rbase + rh * 64 + rloc) * 1536 + h * 64 + kk * 32 + c8;
            GLD16(g, At + kk * 4096 + rh * 2048 + w * 512);
        }
        const unsigned short* Sg = Sbt + (size_t)bh * 4096 + tid * 8;
#pragma unroll
        for (int bi = 0; bi < 2; ++bi)
            GLD16(Sg + bi * 2048, Bt + bi * 2048 + w * 512);
    }
    __syncthreads();

    frag_cd acc[2][4] = {};
#pragma unroll
    for (int kk = 0; kk < 2; ++kk) {
        frag_ab a[2], bfr[4];
#pragma unroll
        for (int i = 0; i < 2; ++i)
            a[i] = *(const frag_ab*)&At[kk * 4096 + (w * 32 + i * 16 + lr) * 32 + quad * 8];
#pragma unroll
        for (int j = 0; j < 4; ++j)
            bfr[j] = *(const frag_ab*)&Bt[kk * 2048 + (j * 16 + lr) * 32 + quad * 8];
#pragma unroll
        for (int i = 0; i < 2; ++i)
#pragma unroll
            for (int j = 0; j < 4; ++j)
                acc[i][j] = __builtin_amdgcn_mfma_f32_16x16x32_bf16(a[i], bfr[j], acc[i][j], 0, 0, 0);
    }

    __syncthreads();
    unsigned short* Cs = Sh + w * 2048;
#pragma unroll
    for (int i = 0; i < 2; ++i)
#pragma unroll
        for (int j = 0; j < 4; ++j)
#pragma unroll
            for (int r = 0; r < 4; ++r)
                Cs[(i * 16 + quad * 4 + r) * 64 + j * 16 + lr] = f2b(acc[i][j][r]);
    const int rl = lane >> 3;
    const int c8o = (lane & 7) * 8;
#pragma unroll
    for (int k = 0; k < 4; ++k) {
        const int row = rl + k * 8;
        ushort8v val = *(const ushort8v*)&Cs[row * 64 + c8o];
        *(ushort8v*)(Ob + (size_t)(rbase + w * 32 + row) * 512 + h * 64 + c8o) = val;
    }
}

// ------- LN over bf16 row (512) in place; wave-shuffle reduction -------
__global__ __launch_bounds__(256) void ln_b16_inplace(
    unsigned short* __restrict__ Y, const float* __restrict__ g,
    const float* __restrict__ bta)
{
    __shared__ float part[8];
    const int row = blockIdx.x;
    const int t = threadIdx.x;
    const int w = t >> 6;
    unsigned short* yr = Y + (size_t)row * Dq;
    const float v0 = b2f(yr[t]), v1 = b2f(yr[t + 256]);
    float s = v0 + v1;
#pragma unroll
    for (int off = 32; off; off >>= 1) s += __shfl_xor(s, off, 64);
    if ((t & 63) == 0) part[w] = s;
    __syncthreads();
    const float mean = (part[0] + part[1] + part[2] + part[3]) * (1.f / Dq);
    const float d0 = v0 - mean, d1 = v1 - mean;
    float q = d0 * d0 + d1 * d1;
#pragma unroll
    for (int off = 32; off; off >>= 1) q += __shfl_xor(q, off, 64);
    if ((t & 63) == 0) part[4 + w] = q;
    __syncthreads();
    const float rstd = rsqrtf((part[4] + part[5] + part[6] + part[7]) * (1.f / Dq) + 1e-5f);
    yr[t] = f2b(d0 * rstd * g[t] + bta[t]);
    yr[t + 256] = f2b(d1 * rstd * g[t + 256] + bta[t + 256]);
}

// ------- LN over bf16 row -> out f32 half-columns (merged rows) -------
__global__ __launch_bounds__(256) void ln_b16_out(
    const unsigned short* __restrict__ Y, const float* __restrict__ g,
    const float* __restrict__ bta, float* __restrict__ out)
{
    __shared__ float part[8];
    const int row = blockIdx.x;
    const int t = threadIdx.x;
    const int w = t >> 6;
    const unsigned short* yr = Y + (size_t)row * Dq;
    const float v0 = b2f(yr[t]), v1 = b2f(yr[t + 256]);
    float s = v0 + v1;
#pragma unroll
    for (int off = 32; off; off >>= 1) s += __shfl_xor(s, off, 64);
    if ((t & 63) == 0) part[w] = s;
    __syncthreads();
    const float mean = (part[0] + part[1] + part[2] + part[3]) * (1.f / Dq);
    const float d0 = v0 - mean, d1 = v1 - mean;
    float q = d0 * d0 + d1 * d1;
#pragma unroll
    for (int off = 32; off; off >>= 1) q += __shfl_xor(q, off, 64);
    if ((t & 63) == 0) part[4 + w] = q;
    __syncthreads();
    const float rstd = rsqrtf((part[4] + part[5] + part[6] + part[7]) * (1.f / Dq) + 1e-5f);
    const int half = row >> 13, br = row & 8191;
    float* orow = out + (size_t)br * 1024 + half * 512;
    orow[t] = d0 * rstd * g[t] + bta[t];
    orow[t + 256] = d1 * rstd * g[t + 256] + bta[t + 256];
}

extern "C" void kernel_launch(void* const* d_in, const int* in_sizes, int n_in,
                              void* d_out, int out_size, void* d_ws, size_t ws_size,
                              hipStream_t stream)
{
    const float* question = (const float*)d_in[0];
    const float* query    = (const float*)d_in[1];
    const float* Wq = (const float*)d_in[2];  const float* bqp = (const float*)d_in[3];
    const float* Wk = (const float*)d_in[4];  const float* bkp = (const float*)d_in[5];
    const float* Wv = (const float*)d_in[6];  const float* bvp = (const float*)d_in[7];
    const float* Wo = (const float*)d_in[8];  const float* bo  = (const float*)d_in[9];
    const float* ln_g = (const float*)d_in[10]; const float* ln_b = (const float*)d_in[11];
    const float* W1 = (const float*)d_in[12]; const float* b1 = (const float*)d_in[13];
    const float* W2 = (const float*)d_in[14]; const float* b2 = (const float*)d_in[15];
    float* out = (float*)d_out;
    char* ws = (char*)d_ws;

    // ---- workspace (~87 MiB) ----
    unsigned short* QKVb  = (unsigned short*)(ws);
    unsigned short* attnb = (unsigned short*)(ws + 48 * MiBu);
    float* Spart          = (float*)(ws + 48 * MiBu);           // dead before attnb
    unsigned short* Xb    = (unsigned short*)(ws + 64 * MiBu);
    unsigned short* xbuf  = (unsigned short*)(ws + 64 * MiBu);  // y0b -> xb -> y
    unsigned short* hb    = (unsigned short*)(ws);              // [16384,2048] bf16
    char* wp = ws + 80 * MiBu + 524288;
    unsigned short* Wqkvb = (unsigned short*)wp;  wp += 1536 * 512 * 2;
    unsigned short* Wob   = (unsigned short*)wp;  wp += 512 * 512 * 2;
    unsigned short* W1b   = (unsigned short*)wp;  wp += 2048 * 512 * 2;
    unsigned short* W2b   = (unsigned short*)wp;  wp += 512 * 2048 * 2;
    unsigned short* Sbt   = (unsigned short*)wp;  wp += 32 * 4096 * 2;
    float* bqkv           = (float*)wp;

    dim3 blk(256);

    convert_all<<<11270, blk, 0, stream>>>(Wq, Wk, Wv, Wo, W1, W2, question, query,
                                           bqp, bkp, bvp,
                                           Wqkvb, Wob, W1b, W2b, Xb, bqkv);

    // QKV: [16384,512]@[1536,512]^T -> bf16 (256^2 8-phase; 384 blocks)
    gemm_256<<<dim3(384), dim3(512), 0, stream>>>(Xb, Wqkvb, bqkv, QKVb,
                                                  Mrows, 1536, 0);

    // S partials (fp32, no atomics) -> reduce+pack bf16 B-layout; attn via MFMA
    s_kernel<<<dim3(32, NSLICE), blk, 0, stream>>>(QKVb, Spart);
    sbt_convert<<<dim3(32, 4), blk, 0, stream>>>(Spart, Sbt);
    attn_mfma<<<dim3(8, 128), blk, 0, stream>>>(QKVb, Sbt, attnb);

    // o-proj + residual(inputs) + bo -> bf16 y0b (256x128 4-phase, 256 blocks)
    gemm_res256<<<dim3(256), dim3(512), 0, stream>>>(attnb, Wob, bo,
                                                     question, query, xbuf, 512);

    // LN1 in place: xb = LN(y0b)
    ln_b16_inplace<<<Mrows, blk, 0, stream>>>(xbuf, ln_g, ln_b);

    // FFN1 full-M: h = relu(xb @ W1^T + b1) -> bf16 [16384,2048] (256^2 8-phase)
    gemm_256<<<dim3(512), dim3(512), 0, stream>>>(xbuf, W1b, b1, hb,
                                                  Mrows, PFq, 1);

    // FFN2 full-M, K=2048: y = h @ W2^T + b2 + xb, bf16 in place (256 blocks)
    gemm_res256<<<dim3(256), dim3(512), 0, stream>>>(hb, W2b, b2,
                                                     nullptr, nullptr, xbuf, 2048);

    // LN2 -> out halves
    ln_b16_out<<<Mrows, blk, 0, stream>>>(xbuf, ln_g, ln_b, out);
}

// Round 4
// 308.627 us; speedup vs baseline: 1.1365x; 1.0299x over previous
//
#include <hip/hip_runtime.h>
#include <stdint.h>

// CrossAttention via linear-attention algebra, both halves merged to M=16384:
//   S = K1^T V1 + K2^T V2 (per b,h; 64x64), shared by both halves.
//   attn = Q @ S ; x = LN(inp + attn@Wo^T + bo) ; out = LN(x + FF(x))
// R10: s_kernel rewrite (latency-bound fix, 55us -> ~10us).
// R11: QKV + FFN1 on gemm_256 (256x256 8-phase, counted vmcnt).
// R12: o-proj + FFN2 on gemm_res256 (256x128 4-phase).
// R13: 2D XCD chunking. R12 counters showed FFN1 FETCH=67.7MB vs 18MB logical:
// the old swizzle gave each XCD a full-M stripe at one n (16MB A streamed
// through a 4MB L2 per XCD, x8 = 128MB of L2 misses). New decode: xcd owns an
// 8-m-tile x all-n rectangle (A-stripe 2MB + B <=2MB fits L2); consecutive
// slots share the B-panel. Applies to gemm_256 and gemm_res256.

#define Bq 4
#define Lq 2048
#define Dq 512
#define PFq 2048
#define Mrows 16384
#define MiBu 1048576ull
#define NSLICE 16

typedef __attribute__((ext_vector_type(8))) short frag_ab;
typedef __attribute__((ext_vector_type(4))) float frag_cd;
typedef __attribute__((ext_vector_type(8))) unsigned short ushort8v;

__device__ __forceinline__ unsigned short f2b(float f) {
    union { float f; uint32_t u; } x; x.f = f;
    uint32_t r = x.u + 0x7fffu + ((x.u >> 16) & 1u);
    return (unsigned short)(r >> 16);
}
__device__ __forceinline__ float b2f(unsigned short u) {
    union { uint32_t u; float f; } x; x.u = ((uint32_t)u) << 16;
    return x.f;
}

#define GLD16(g, l)                                                              \
    __builtin_amdgcn_global_load_lds(                                            \
        (const __attribute__((address_space(1))) void*)(const void*)(g),         \
        (__attribute__((address_space(3))) void*)(void*)(l), 16, 0, 0)

// One stage unit: 128 rows x 64 k-cols bf16 (2x global_load_lds_dwordx4/thread)
#define STG(BUFOFS, REGOFS, GB, ROWOFS, TILE, KS)                                \
    { GLD16((GB) + (size_t)(ROWOFS) * (KS) + (TILE) * 64,                        \
            Sh + (BUFOFS) + (REGOFS) + ld);                                      \
      GLD16((GB) + ((size_t)(ROWOFS) + 64) * (KS) + (TILE) * 64,                 \
            Sh + (BUFOFS) + (REGOFS) + ld + 4096); }

#define VMW(N) asm volatile("s_waitcnt vmcnt(" #N ")" ::: "memory")

// One phase: ds-read 2 M-frags (+8 B-frags if LOADB), issue stages, counted
// wait, barrier, 16 MFMA under setprio, barrier.
#define PHASE(CB, M0, LOADB, STAGE_STMT, WAIT_STMT)                              \
    {                                                                            \
        frag_ab a00 = *(const frag_ab*)&Sh[(CB) + (wm + (M0)*16 + lr) * 64 + xo0];      \
        frag_ab a01 = *(const frag_ab*)&Sh[(CB) + (wm + (M0)*16 + lr) * 64 + xo1];      \
        frag_ab a10 = *(const frag_ab*)&Sh[(CB) + (wm + (M0)*16 + 16 + lr) * 64 + xo0]; \
        frag_ab a11 = *(const frag_ab*)&Sh[(CB) + (wm + (M0)*16 + 16 + lr) * 64 + xo1]; \
        if (LOADB) {                                                             \
            _Pragma("unroll")                                                    \
            for (int j = 0; j < 4; ++j) {                                        \
                bf[j][0] = *(const frag_ab*)&Sh[(CB) + 16384 + (wn + j*16 + lr)*64 + xo0]; \
                bf[j][1] = *(const frag_ab*)&Sh[(CB) + 16384 + (wn + j*16 + lr)*64 + xo1]; \
            }                                                                    \
        }                                                                        \
        STAGE_STMT;                                                              \
        WAIT_STMT;                                                               \
        __builtin_amdgcn_sched_barrier(0);                                       \
        __builtin_amdgcn_s_barrier();                                            \
        asm volatile("s_waitcnt lgkmcnt(0)" ::: "memory");                       \
        __builtin_amdgcn_sched_barrier(0);                                       \
        __builtin_amdgcn_s_setprio(1);                                           \
        _Pragma("unroll")                                                        \
        for (int j = 0; j < 4; ++j) {                                            \
            acc[(M0)][j]   = __builtin_amdgcn_mfma_f32_16x16x32_bf16(a00, bf[j][0], acc[(M0)][j], 0,0,0);   \
            acc[(M0)][j]   = __builtin_amdgcn_mfma_f32_16x16x32_bf16(a01, bf[j][1], acc[(M0)][j], 0,0,0);   \
            acc[(M0)+1][j] = __builtin_amdgcn_mfma_f32_16x16x32_bf16(a10, bf[j][0], acc[(M0)+1][j], 0,0,0); \
            acc[(M0)+1][j] = __builtin_amdgcn_mfma_f32_16x16x32_bf16(a11, bf[j][1], acc[(M0)+1][j], 0,0,0); \
        }                                                                        \
        __builtin_amdgcn_s_setprio(0);                                           \
        __builtin_amdgcn_sched_barrier(0);                                       \
        __builtin_amdgcn_s_barrier();                                            \
        __builtin_amdgcn_sched_barrier(0);                                       \
    }

// ================== 256x256 8-phase bf16 GEMM (K=512 fixed) ==================
// outB = A[M,512]b @ W[N,512]b^T + bias (+relu). 512 threads, 8 waves (2Mx4N),
// per-wave 128x64 output. LDS 128 KiB: 2 buf x (A 256x64 + B 256x64) bf16.
// grid: 1D, (M/256)*(N/256) blocks; 2D XCD chunking (requires (M>>8)%8==0).
__global__ __launch_bounds__(512, 2) void gemm_256(
    const unsigned short* __restrict__ A, const unsigned short* __restrict__ Wt,
    const float* __restrict__ bias, unsigned short* __restrict__ outB,
    int M, int N, int relu)
{
    __shared__ __align__(16) unsigned short Sh[65536];   // 128 KiB
    const int tid = threadIdx.x;
    const int lane = tid & 63;
    const int w = tid >> 6;              // 0..7
    const int wm = (w >> 2) * 128;       // 0 / 128
    const int wn = (w & 3) * 64;         // 0..192
    const int lr = lane & 15;
    const int quad = lane >> 4;
    const int xo0 = ((quad ^ (lr & 7)) << 3);
    const int xo1 = (((4 | quad) ^ (lr & 7)) << 3);

    // 2D XCD chunking: xcd owns m-tiles [xcd*mloc, xcd*mloc+mloc) x all n.
    // Consecutive slots walk m fastest -> co-resident blocks share B-panel.
    const int b0 = blockIdx.x;
    const int xcd = b0 & 7, slot = b0 >> 3;
    const int mloc = (M >> 8) >> 3;
    const size_t bm = (size_t)(xcd * mloc + slot % mloc) * 256;
    const size_t bn = (size_t)(slot / mloc) * 256;

    const int ar = tid >> 3;                         // 0..63
    const int sw = ((tid & 7) ^ (ar & 7)) << 3;      // pre-swizzled k-chunk
    const unsigned short* Ag = A  + (bm + ar) * (size_t)512 + sw;
    const unsigned short* Bg = Wt + (bn + ar) * (size_t)512 + sw;
    const int ld = tid * 8;                          // LDS elem offset (16B/lane)

    frag_cd acc[8][4] = {};
    frag_ab bf[4][2];

    // prologue: 0.B0 0.B1 0.A0 0.A1 1.B0 1.B1
    STG(0,     16384, Bg, 0,   0, 512);
    STG(0,     24576, Bg, 128, 0, 512);
    STG(0,     0,     Ag, 0,   0, 512);
    STG(0,     8192,  Ag, 128, 0, 512);
    STG(32768, 16384, Bg, 0,   1, 512);
    STG(32768, 24576, Bg, 128, 1, 512);
    VMW(4);
    __builtin_amdgcn_sched_barrier(0);
    __builtin_amdgcn_s_barrier();
    __builtin_amdgcn_sched_barrier(0);

    for (int I = 0; I < 3; ++I) {
        const int tb = 2 * I + 1, tc = 2 * I + 2, td = 2 * I + 3;
        PHASE(0,     0, 1, STG(32768, 0,     Ag, 0,   tb, 512), (void)0);
        PHASE(0,     2, 0, STG(32768, 8192,  Ag, 128, tb, 512), (void)0);
        PHASE(0,     4, 0, STG(0,     16384, Bg, 0,   tc, 512), (void)0);
        PHASE(0,     6, 0, STG(0,     24576, Bg, 128, tc, 512), VMW(4));
        PHASE(32768, 0, 1, STG(0,     0,     Ag, 0,   tc, 512), (void)0);
        PHASE(32768, 2, 0, STG(0,     8192,  Ag, 128, tc, 512), (void)0);
        PHASE(32768, 4, 0, STG(32768, 16384, Bg, 0,   td, 512), (void)0);
        PHASE(32768, 6, 0, STG(32768, 24576, Bg, 128, td, 512), VMW(4));
    }
    PHASE(0,     0, 1, STG(32768, 0,    Ag, 0,   7, 512), (void)0);
    PHASE(0,     2, 0, STG(32768, 8192, Ag, 128, 7, 512), (void)0);
    PHASE(0,     4, 0, (void)0, (void)0);
    PHASE(0,     6, 0, (void)0, VMW(0));
    PHASE(32768, 0, 1, (void)0, (void)0);
    PHASE(32768, 2, 0, (void)0, (void)0);
    PHASE(32768, 4, 0, (void)0, (void)0);
    PHASE(32768, 6, 0, (void)0, (void)0);

    // epilogue: wave w stages its 128x64 to Sh[w*8192], then 16B/lane stores
    float bv[4];
#pragma unroll
    for (int j = 0; j < 4; ++j) bv[j] = bias[(int)bn + wn + j * 16 + lr];
    unsigned short* Cs = Sh + w * 8192;
#pragma unroll
    for (int m = 0; m < 8; ++m)
#pragma unroll
        for (int j = 0; j < 4; ++j)
#pragma unroll
            for (int r = 0; r < 4; ++r) {
                float v = acc[m][j][r] + bv[j];
                if (relu) v = fmaxf(v, 0.f);
                Cs[(m * 16 + quad * 4 + r) * 64 + j * 16 + lr] = f2b(v);
            }
    const int rl = lane >> 3, c8 = (lane & 7) * 8;
#pragma unroll
    for (int k = 0; k < 16; ++k) {
        const int row = rl + k * 8;
        ushort8v val = *(const ushort8v*)&Cs[row * 64 + c8];
        *(ushort8v*)(outB + (size_t)(bm + wm + row) * N + bn + wn + c8) = val;
    }
}

// ========== 256x128 4-phase residual GEMM, N=512 fixed, runtime K ============
// outB = A@W^T + bias + residual. resA/resB f32 (rows <8192 / >=8192);
// resA==null: residual = b2f(outB[idx]) (in-place). grid 256 blocks, 512 thr.
// LDS 96 KiB: 2 buf x (A 256x64 = 32K + B 128x64 = 16K). 8 waves 4Mx2N,
// per-wave 64x64 (acc[4][4]).
__global__ __launch_bounds__(512, 2) void gemm_res256(
    const unsigned short* __restrict__ A, const unsigned short* __restrict__ Wt,
    const float* __restrict__ bias,
    const float* __restrict__ resA, const float* __restrict__ resB,
    unsigned short* __restrict__ outB, int K)
{
    __shared__ __align__(16) unsigned short Sh[49152];   // 96 KiB
    const int tid = threadIdx.x;
    const int lane = tid & 63;
    const int w = tid >> 6;              // 0..7
    const int wm = (w >> 1) * 64;        // 0/64/128/192
    const int wn = (w & 1) * 64;         // 0/64
    const int lr = lane & 15;
    const int quad = lane >> 4;
    const int xo0 = ((quad ^ (lr & 7)) << 3);
    const int xo1 = (((4 | quad) ^ (lr & 7)) << 3);

    // 2D XCD chunking: xcd owns 8 m-tiles x all 4 n-tiles (slot 0..31)
    const int b0 = blockIdx.x;
    const int xcd = b0 & 7, slot = b0 >> 3;
    const size_t bm = (size_t)(xcd * 8 + (slot & 7)) * 256;
    const size_t bn = (size_t)(slot >> 3) * 128;

    const int ar = tid >> 3;
    const int sw = ((tid & 7) ^ (ar & 7)) << 3;
    const unsigned short* Ag = A  + (bm + ar) * (size_t)K + sw;
    const unsigned short* Bg = Wt + (bn + ar) * (size_t)K + sw;
    const int ld = tid * 8;

    frag_cd acc[4][4] = {};
    frag_ab bf[4][2];

    // prologue: aB aA0 aA1 bB ; wait all but bB
    STG(0,     16384, Bg, 0,   0, K);
    STG(0,     0,     Ag, 0,   0, K);
    STG(0,     8192,  Ag, 128, 0, K);
    STG(24576, 16384, Bg, 0,   1, K);
    VMW(2);
    __builtin_amdgcn_sched_barrier(0);
    __builtin_amdgcn_s_barrier();
    __builtin_amdgcn_sched_barrier(0);

    const int nIter = K >> 7;            // 2 K-tiles per iteration
    for (int I = 0; I < nIter - 1; ++I) {
        const int tb = 2 * I + 1, tc = 2 * I + 2, td = 2 * I + 3;
        PHASE(0,     0, 1, { STG(24576, 0, Ag, 0, tb, K); STG(24576, 8192, Ag, 128, tb, K); }, (void)0);
        PHASE(0,     2, 0, STG(0, 16384, Bg, 0, tc, K), VMW(2));
        PHASE(24576, 0, 1, { STG(0, 0, Ag, 0, tc, K); STG(0, 8192, Ag, 128, tc, K); }, (void)0);
        PHASE(24576, 2, 0, STG(24576, 16384, Bg, 0, td, K), VMW(2));
    }
    {   // tail: computes tiles 2(nIter-1), 2nIter-1; only b's A left to stage
        const int tb = (K >> 6) - 1;
        PHASE(0,     0, 1, { STG(24576, 0, Ag, 0, tb, K); STG(24576, 8192, Ag, 128, tb, K); }, (void)0);
        PHASE(0,     2, 0, (void)0, VMW(0));
        PHASE(24576, 0, 1, (void)0, (void)0);
        PHASE(24576, 2, 0, (void)0, (void)0);
    }

    // epilogue: wave w stages its 64x64 to Sh[w*4096]; residual added post-LDS
    float bv[4];
#pragma unroll
    for (int j = 0; j < 4; ++j) bv[j] = bias[(int)bn + wn + j * 16 + lr];
    unsigned short* Cs = Sh + w * 4096;
#pragma unroll
    for (int m = 0; m < 4; ++m)
#pragma unroll
        for (int j = 0; j < 4; ++j)
#pragma unroll
            for (int r = 0; r < 4; ++r)
                Cs[(m * 16 + quad * 4 + r) * 64 + j * 16 + lr] = f2b(acc[m][j][r] + bv[j]);
    const int rl = lane >> 3, c8 = (lane & 7) * 8;
#pragma unroll
    for (int k = 0; k < 8; ++k) {
        const int row = rl + k * 8;
        const int grow = (int)bm + wm + row;
        const size_t idx = (size_t)grow * 512 + bn + wn + c8;
        ushort8v val = *(const ushort8v*)&Cs[row * 64 + c8];
        float vv[8];
#pragma unroll
        for (int t = 0; t < 8; ++t) vv[t] = b2f(val[t]);
        if (resA) {
            const float* rp = (grow < 8192) ? resA + idx : resB + idx - (size_t)8192 * 512;
            float4 ra = *(const float4*)(rp);
            float4 rb = *(const float4*)(rp + 4);
            vv[0] += ra.x; vv[1] += ra.y; vv[2] += ra.z; vv[3] += ra.w;
            vv[4] += rb.x; vv[5] += rb.y; vv[6] += rb.z; vv[7] += rb.w;
        } else {
            ushort8v old = *(const ushort8v*)(outB + idx);
#pragma unroll
            for (int t = 0; t < 8; ++t) vv[t] += b2f(old[t]);
        }
        ushort8v o;
#pragma unroll
        for (int t = 0; t < 8; ++t) o[t] = f2b(vv[t]);
        *(ushort8v*)(outB + idx) = o;
    }
}

// -------- merged fp32->bf16 converts + QKV bias concat --------
__global__ __launch_bounds__(256) void convert_all(
    const float* __restrict__ Wq, const float* __restrict__ Wk,
    const float* __restrict__ Wv, const float* __restrict__ Wo,
    const float* __restrict__ W1, const float* __restrict__ W2,
    const float* __restrict__ question, const float* __restrict__ query,
    const float* __restrict__ bqp, const float* __restrict__ bkp,
    const float* __restrict__ bvp,
    unsigned short* __restrict__ Wqkvb, unsigned short* __restrict__ Wob,
    unsigned short* __restrict__ W1b, unsigned short* __restrict__ W2b,
    unsigned short* __restrict__ Xb, float* __restrict__ bqkv)
{
    const int b = blockIdx.x;
    const float* src; unsigned short* dst; size_t off;
    if (b < 256)        { src = Wq; dst = Wqkvb;          off = (size_t)b * 1024; }
    else if (b < 512)   { src = Wk; dst = Wqkvb + 262144; off = (size_t)(b - 256) * 1024; }
    else if (b < 768)   { src = Wv; dst = Wqkvb + 524288; off = (size_t)(b - 512) * 1024; }
    else if (b < 1024)  { src = Wo; dst = Wob;            off = (size_t)(b - 768) * 1024; }
    else if (b < 2048)  { src = W1; dst = W1b;            off = (size_t)(b - 1024) * 1024; }
    else if (b < 3072)  { src = W2; dst = W2b;            off = (size_t)(b - 2048) * 1024; }
    else if (b < 7168)  { src = question; dst = Xb;       off = (size_t)(b - 3072) * 1024; }
    else if (b < 11264) { src = query; dst = Xb + 4194304; off = (size_t)(b - 7168) * 1024; }
    else {
        const int n = (b - 11264) * 256 + threadIdx.x;   // 0..1535
        bqkv[n] = (n < 512) ? bqp[n] : (n < 1024) ? bkp[n - 512] : bvp[n - 1024];
        return;
    }
    const size_t idx = off + threadIdx.x * 4;
    float4 v = *(const float4*)(src + idx);
    ushort4 o;
    o.x = f2b(v.x); o.y = f2b(v.y); o.z = f2b(v.z); o.w = f2b(v.w);
    *(ushort4*)(dst + idx) = o;
}

// ------- Spart[bh][slice] = sum over 256 l-rows of K^T outer V (merged QKV) ----
__global__ __launch_bounds__(256) void s_kernel(
    const unsigned short* __restrict__ QKV, float* __restrict__ Spart)
{
    const int bh = blockIdx.x;           // 0..31
    const int sl = blockIdx.y;           // 0..NSLICE-1
    const int b = bh >> 3, h = bh & 7;
    const int pass = sl >> 3;
    const int l0 = (sl & 7) * 256;
    __shared__ float Ks[64][64];
    __shared__ float Vs[64][64];
    const int tid = threadIdx.x;
    const int tx = tid & 15, ty = tid >> 4;
    const int srow = tid >> 3;
    const int scol = (tid & 7) * 8;
    const size_t rowbase = (size_t)pass * 8192 + (size_t)b * Lq + l0;

    float acc[4][4] = {};

    for (int t0 = 0; t0 < 256; t0 += 64) {
        const unsigned short* kp0 = QKV + (rowbase + t0 + srow) * 1536 + 512 + h * 64 + scol;
        const unsigned short* kp1 = kp0 + (size_t)32 * 1536;
        ushort8v k0 = *(const ushort8v*)kp0;
        ushort8v v0 = *(const ushort8v*)(kp0 + 512);
        ushort8v k1 = *(const ushort8v*)kp1;
        ushort8v v1 = *(const ushort8v*)(kp1 + 512);
        __syncthreads();
#pragma unroll
        for (int e = 0; e < 8; ++e) {
            Ks[srow][scol + e]      = b2f(k0[e]);
            Vs[srow][scol + e]      = b2f(v0[e]);
            Ks[srow + 32][scol + e] = b2f(k1[e]);
            Vs[srow + 32][scol + e] = b2f(v1[e]);
        }
        __syncthreads();
#pragma unroll 4
        for (int rr = 0; rr < 64; ++rr) {
            const float4 kf = *(const float4*)&Ks[rr][ty * 4];
            const float4 vf = *(const float4*)&Vs[rr][tx * 4];
            acc[0][0] = fmaf(kf.x, vf.x, acc[0][0]);
            acc[0][1] = fmaf(kf.x, vf.y, acc[0][1]);
            acc[0][2] = fmaf(kf.x, vf.z, acc[0][2]);
            acc[0][3] = fmaf(kf.x, vf.w, acc[0][3]);
            acc[1][0] = fmaf(kf.y, vf.x, acc[1][0]);
            acc[1][1] = fmaf(kf.y, vf.y, acc[1][1]);
            acc[1][2] = fmaf(kf.y, vf.z, acc[1][2]);
            acc[1][3] = fmaf(kf.y, vf.w, acc[1][3]);
            acc[2][0] = fmaf(kf.z, vf.x, acc[2][0]);
            acc[2][1] = fmaf(kf.z, vf.y, acc[2][1]);
            acc[2][2] = fmaf(kf.z, vf.z, acc[2][2]);
            acc[2][3] = fmaf(kf.z, vf.w, acc[2][3]);
            acc[3][0] = fmaf(kf.w, vf.x, acc[3][0]);
            acc[3][1] = fmaf(kf.w, vf.y, acc[3][1]);
            acc[3][2] = fmaf(kf.w, vf.z, acc[3][2]);
            acc[3][3] = fmaf(kf.w, vf.w, acc[3][3]);
        }
    }

    float* Sp = Spart + ((size_t)bh * NSLICE + sl) * 4096;
#pragma unroll
    for (int i = 0; i < 4; ++i) {
        float4 o = make_float4(acc[i][0], acc[i][1], acc[i][2], acc[i][3]);
        *(float4*)(Sp + (ty * 4 + i) * 64 + tx * 4) = o;
    }
}

// ------- reduce NSLICE partials -> Sbt bf16, B-layout [bh][khalf][n][kj] -------
__global__ __launch_bounds__(256) void sbt_convert(
    const float* __restrict__ Spart, unsigned short* __restrict__ Sbt)
{
    const int bh = blockIdx.x;
    const int uo = blockIdx.y;           // 0..3
    const float* Sp = Spart + (size_t)bh * (NSLICE * 4096);
    unsigned short* Dp = Sbt + (size_t)bh * 4096;
    const int t = threadIdx.x;
#pragma unroll
    for (int u = 0; u < 4; ++u) {
        const int d = (uo * 4 + u) * 256 + t;
        float v = 0.f;
#pragma unroll
        for (int s = 0; s < NSLICE; ++s) v += Sp[(size_t)s * 4096 + d];
        const int row = d >> 6, col = d & 63;
        Dp[(row >> 5) * 2048 + col * 32 + (row & 31)] = f2b(v);
    }
}

// ------- attn = Q @ S_bh via MFMA; block: 128 rows x 64 cols (one head) -------
__global__ __launch_bounds__(256) void attn_mfma(
    const unsigned short* __restrict__ QKV, const unsigned short* __restrict__ Sbt,
    unsigned short* __restrict__ Ob)
{
    __shared__ __align__(16) unsigned short Sh[2 * 128 * 32 + 2 * 64 * 32];
    unsigned short* At = Sh;
    unsigned short* Bt = Sh + 2 * 128 * 32;
    const int h = blockIdx.x;
    const int rbase = blockIdx.y * 128;
    const int b = (rbase >> 11) & 3;
    const int bh = b * 8 + h;
    const int tid = threadIdx.x;
    const int lane = tid & 63;
    const int w = tid >> 6;
    const int lr = lane & 15;
    const int quad = lane >> 4;

    {
        const int rloc = tid >> 2, c8 = (tid & 3) * 8;
#pragma unroll
        for (int it = 0; it < 4; ++it) {
            const int kk = it & 1, rh = it >> 1;
            const unsigned short* g = QKV +
                ((size_t)rbase + rh * 64 + rloc) * 1536 + h * 64 + kk * 32 + c8;
            GLD16(g, At + kk * 4096 + rh * 2048 + w * 512);
        }
        const unsigned short* Sg = Sbt + (size_t)bh * 4096 + tid * 8;
#pragma unroll
        for (int bi = 0; bi < 2; ++bi)
            GLD16(Sg + bi * 2048, Bt + bi * 2048 + w * 512);
    }
    __syncthreads();

    frag_cd acc[2][4] = {};
#pragma unroll
    for (int kk = 0; kk < 2; ++kk) {
        frag_ab a[2], bfr[4];
#pragma unroll
        for (int i = 0; i < 2; ++i)
            a[i] = *(const frag_ab*)&At[kk * 4096 + (w * 32 + i * 16 + lr) * 32 + quad * 8];
#pragma unroll
        for (int j = 0; j < 4; ++j)
            bfr[j] = *(const frag_ab*)&Bt[kk * 2048 + (j * 16 + lr) * 32 + quad * 8];
#pragma unroll
        for (int i = 0; i < 2; ++i)
#pragma unroll
            for (int j = 0; j < 4; ++j)
                acc[i][j] = __builtin_amdgcn_mfma_f32_16x16x32_bf16(a[i], bfr[j], acc[i][j], 0, 0, 0);
    }

    __syncthreads();
    unsigned short* Cs = Sh + w * 2048;
#pragma unroll
    for (int i = 0; i < 2; ++i)
#pragma unroll
        for (int j = 0; j < 4; ++j)
#pragma unroll
            for (int r = 0; r < 4; ++r)
                Cs[(i * 16 + quad * 4 + r) * 64 + j * 16 + lr] = f2b(acc[i][j][r]);
    const int rl = lane >> 3;
    const int c8o = (lane & 7) * 8;
#pragma unroll
    for (int k = 0; k < 4; ++k) {
        const int row = rl + k * 8;
        ushort8v val = *(const ushort8v*)&Cs[row * 64 + c8o];
        *(ushort8v*)(Ob + (size_t)(rbase + w * 32 + row) * 512 + h * 64 + c8o) = val;
    }
}

// ------- LN over bf16 row (512) in place; wave-shuffle reduction -------
__global__ __launch_bounds__(256) void ln_b16_inplace(
    unsigned short* __restrict__ Y, const float* __restrict__ g,
    const float* __restrict__ bta)
{
    __shared__ float part[8];
    const int row = blockIdx.x;
    const int t = threadIdx.x;
    const int w = t >> 6;
    unsigned short* yr = Y + (size_t)row * Dq;
    const float v0 = b2f(yr[t]), v1 = b2f(yr[t + 256]);
    float s = v0 + v1;
#pragma unroll
    for (int off = 32; off; off >>= 1) s += __shfl_xor(s, off, 64);
    if ((t & 63) == 0) part[w] = s;
    __syncthreads();
    const float mean = (part[0] + part[1] + part[2] + part[3]) * (1.f / Dq);
    const float d0 = v0 - mean, d1 = v1 - mean;
    float q = d0 * d0 + d1 * d1;
#pragma unroll
    for (int off = 32; off; off >>= 1) q += __shfl_xor(q, off, 64);
    if ((t & 63) == 0) part[4 + w] = q;
    __syncthreads();
    const float rstd = rsqrtf((part[4] + part[5] + part[6] + part[7]) * (1.f / Dq) + 1e-5f);
    yr[t] = f2b(d0 * rstd * g[t] + bta[t]);
    yr[t + 256] = f2b(d1 * rstd * g[t + 256] + bta[t + 256]);
}

// ------- LN over bf16 row -> out f32 half-columns (merged rows) -------
__global__ __launch_bounds__(256) void ln_b16_out(
    const unsigned short* __restrict__ Y, const float* __restrict__ g,
    const float* __restrict__ bta, float* __restrict__ out)
{
    __shared__ float part[8];
    const int row = blockIdx.x;
    const int t = threadIdx.x;
    const int w = t >> 6;
    const unsigned short* yr = Y + (size_t)row * Dq;
    const float v0 = b2f(yr[t]), v1 = b2f(yr[t + 256]);
    float s = v0 + v1;
#pragma unroll
    for (int off = 32; off; off >>= 1) s += __shfl_xor(s, off, 64);
    if ((t & 63) == 0) part[w] = s;
    __syncthreads();
    const float mean = (part[0] + part[1] + part[2] + part[3]) * (1.f / Dq);
    const float d0 = v0 - mean, d1 = v1 - mean;
    float q = d0 * d0 + d1 * d1;
#pragma unroll
    for (int off = 32; off; off >>= 1) q += __shfl_xor(q, off, 64);
    if ((t & 63) == 0) part[4 + w] = q;
    __syncthreads();
    const float rstd = rsqrtf((part[4] + part[5] + part[6] + part[7]) * (1.f / Dq) + 1e-5f);
    const int half = row >> 13, br = row & 8191;
    float* orow = out + (size_t)br * 1024 + half * 512;
    orow[t] = d0 * rstd * g[t] + bta[t];
    orow[t + 256] = d1 * rstd * g[t + 256] + bta[t + 256];
}

extern "C" void kernel_launch(void* const* d_in, const int* in_sizes, int n_in,
                              void* d_out, int out_size, void* d_ws, size_t ws_size,
                              hipStream_t stream)
{
    const float* question = (const float*)d_in[0];
    const float* query    = (const float*)d_in[1];
    const float* Wq = (const float*)d_in[2];  const float* bqp = (const float*)d_in[3];
    const float* Wk = (const float*)d_in[4];  const float* bkp = (const float*)d_in[5];
    const float* Wv = (const float*)d_in[6];  const float* bvp = (const float*)d_in[7];
    const float* Wo = (const float*)d_in[8];  const float* bo  = (const float*)d_in[9];
    const float* ln_g = (const float*)d_in[10]; const float* ln_b = (const float*)d_in[11];
    const float* W1 = (const float*)d_in[12]; const float* b1 = (const float*)d_in[13];
    const float* W2 = (const float*)d_in[14]; const float* b2 = (const float*)d_in[15];
    float* out = (float*)d_out;
    char* ws = (char*)d_ws;

    // ---- workspace (~87 MiB) ----
    unsigned short* QKVb  = (unsigned short*)(ws);
    unsigned short* attnb = (unsigned short*)(ws + 48 * MiBu);
    float* Spart          = (float*)(ws + 48 * MiBu);           // dead before attnb
    unsigned short* Xb    = (unsigned short*)(ws + 64 * MiBu);
    unsigned short* xbuf  = (unsigned short*)(ws + 64 * MiBu);  // y0b -> xb -> y
    unsigned short* hb    = (unsigned short*)(ws);              // [16384,2048] bf16
    char* wp = ws + 80 * MiBu + 524288;
    unsigned short* Wqkvb = (unsigned short*)wp;  wp += 1536 * 512 * 2;
    unsigned short* Wob   = (unsigned short*)wp;  wp += 512 * 512 * 2;
    unsigned short* W1b   = (unsigned short*)wp;  wp += 2048 * 512 * 2;
    unsigned short* W2b   = (unsigned short*)wp;  wp += 512 * 2048 * 2;
    unsigned short* Sbt   = (unsigned short*)wp;  wp += 32 * 4096 * 2;
    float* bqkv           = (float*)wp;

    dim3 blk(256);

    convert_all<<<11270, blk, 0, stream>>>(Wq, Wk, Wv, Wo, W1, W2, question, query,
                                           bqp, bkp, bvp,
                                           Wqkvb, Wob, W1b, W2b, Xb, bqkv);

    // QKV: [16384,512]@[1536,512]^T -> bf16 (256^2 8-phase; 384 blocks)
    gemm_256<<<dim3(384), dim3(512), 0, stream>>>(Xb, Wqkvb, bqkv, QKVb,
                                                  Mrows, 1536, 0);

    // S partials (fp32, no atomics) -> reduce+pack bf16 B-layout; attn via MFMA
    s_kernel<<<dim3(32, NSLICE), blk, 0, stream>>>(QKVb, Spart);
    sbt_convert<<<dim3(32, 4), blk, 0, stream>>>(Spart, Sbt);
    attn_mfma<<<dim3(8, 128), blk, 0, stream>>>(QKVb, Sbt, attnb);

    // o-proj + residual(inputs) + bo -> bf16 y0b (256x128 4-phase, 256 blocks)
    gemm_res256<<<dim3(256), dim3(512), 0, stream>>>(attnb, Wob, bo,
                                                     question, query, xbuf, 512);

    // LN1 in place: xb = LN(y0b)
    ln_b16_inplace<<<Mrows, blk, 0, stream>>>(xbuf, ln_g, ln_b);

    // FFN1 full-M: h = relu(xb @ W1^T + b1) -> bf16 [16384,2048] (256^2 8-phase)
    gemm_256<<<dim3(512), dim3(512), 0, stream>>>(xbuf, W1b, b1, hb,
                                                  Mrows, PFq, 1);

    // FFN2 full-M, K=2048: y = h @ W2^T + b2 + xb, bf16 in place (256 blocks)
    gemm_res256<<<dim3(256), dim3(512), 0, stream>>>(hb, W2b, b2,
                                                     nullptr, nullptr, xbuf, 2048);

    // LN2 -> out halves
    ln_b16_out<<<Mrows, blk, 0, stream>>>(xbuf, ln_g, ln_b, out);
}

// Round 5
// 300.987 us; speedup vs baseline: 1.1654x; 1.0254x over previous
//
#include <hip/hip_runtime.h>
#include <stdint.h>

// CrossAttention via linear-attention algebra, both halves merged to M=16384:
//   S = K1^T V1 + K2^T V2 (per b,h; 64x64), shared by both halves.
//   attn = Q @ S ; x = LN(inp + attn@Wo^T + bo) ; out = LN(x + FF(x))
// R10: s_kernel rewrite (latency-bound fix). R11: gemm_256 8-phase.
// R12: gemm_res256 4-phase. R13: 2D XCD chunking (FETCH 67.7->24.7MB).
// R14: QKV tail-balance. QKV ran 384 blocks of the 256^2 kernel on 256 CUs at
// 1 block/CU -> round 2 half idle (2 rounds paid for 1.5 of work). gemm_res256
// generalized to gemm_n128 (runtime N, mode {0=bias,1=f32 residual,2=inplace});
// QKV now 768 blocks (64 m x 12 n) = exactly 3 balanced rounds.

#define Bq 4
#define Lq 2048
#define Dq 512
#define PFq 2048
#define Mrows 16384
#define MiBu 1048576ull
#define NSLICE 16

typedef __attribute__((ext_vector_type(8))) short frag_ab;
typedef __attribute__((ext_vector_type(4))) float frag_cd;
typedef __attribute__((ext_vector_type(8))) unsigned short ushort8v;

__device__ __forceinline__ unsigned short f2b(float f) {
    union { float f; uint32_t u; } x; x.f = f;
    uint32_t r = x.u + 0x7fffu + ((x.u >> 16) & 1u);
    return (unsigned short)(r >> 16);
}
__device__ __forceinline__ float b2f(unsigned short u) {
    union { uint32_t u; float f; } x; x.u = ((uint32_t)u) << 16;
    return x.f;
}

#define GLD16(g, l)                                                              \
    __builtin_amdgcn_global_load_lds(                                            \
        (const __attribute__((address_space(1))) void*)(const void*)(g),         \
        (__attribute__((address_space(3))) void*)(void*)(l), 16, 0, 0)

// One stage unit: 128 rows x 64 k-cols bf16 (2x global_load_lds_dwordx4/thread)
#define STG(BUFOFS, REGOFS, GB, ROWOFS, TILE, KS)                                \
    { GLD16((GB) + (size_t)(ROWOFS) * (KS) + (TILE) * 64,                        \
            Sh + (BUFOFS) + (REGOFS) + ld);                                      \
      GLD16((GB) + ((size_t)(ROWOFS) + 64) * (KS) + (TILE) * 64,                 \
            Sh + (BUFOFS) + (REGOFS) + ld + 4096); }

#define VMW(N) asm volatile("s_waitcnt vmcnt(" #N ")" ::: "memory")

// One phase: ds-read 2 M-frags (+8 B-frags if LOADB), issue stages, counted
// wait, barrier, 16 MFMA under setprio, barrier.
#define PHASE(CB, M0, LOADB, STAGE_STMT, WAIT_STMT)                              \
    {                                                                            \
        frag_ab a00 = *(const frag_ab*)&Sh[(CB) + (wm + (M0)*16 + lr) * 64 + xo0];      \
        frag_ab a01 = *(const frag_ab*)&Sh[(CB) + (wm + (M0)*16 + lr) * 64 + xo1];      \
        frag_ab a10 = *(const frag_ab*)&Sh[(CB) + (wm + (M0)*16 + 16 + lr) * 64 + xo0]; \
        frag_ab a11 = *(const frag_ab*)&Sh[(CB) + (wm + (M0)*16 + 16 + lr) * 64 + xo1]; \
        if (LOADB) {                                                             \
            _Pragma("unroll")                                                    \
            for (int j = 0; j < 4; ++j) {                                        \
                bf[j][0] = *(const frag_ab*)&Sh[(CB) + 16384 + (wn + j*16 + lr)*64 + xo0]; \
                bf[j][1] = *(const frag_ab*)&Sh[(CB) + 16384 + (wn + j*16 + lr)*64 + xo1]; \
            }                                                                    \
        }                                                                        \
        STAGE_STMT;                                                              \
        WAIT_STMT;                                                               \
        __builtin_amdgcn_sched_barrier(0);                                       \
        __builtin_amdgcn_s_barrier();                                            \
        asm volatile("s_waitcnt lgkmcnt(0)" ::: "memory");                       \
        __builtin_amdgcn_sched_barrier(0);                                       \
        __builtin_amdgcn_s_setprio(1);                                           \
        _Pragma("unroll")                                                        \
        for (int j = 0; j < 4; ++j) {                                            \
            acc[(M0)][j]   = __builtin_amdgcn_mfma_f32_16x16x32_bf16(a00, bf[j][0], acc[(M0)][j], 0,0,0);   \
            acc[(M0)][j]   = __builtin_amdgcn_mfma_f32_16x16x32_bf16(a01, bf[j][1], acc[(M0)][j], 0,0,0);   \
            acc[(M0)+1][j] = __builtin_amdgcn_mfma_f32_16x16x32_bf16(a10, bf[j][0], acc[(M0)+1][j], 0,0,0); \
            acc[(M0)+1][j] = __builtin_amdgcn_mfma_f32_16x16x32_bf16(a11, bf[j][1], acc[(M0)+1][j], 0,0,0); \
        }                                                                        \
        __builtin_amdgcn_s_setprio(0);                                           \
        __builtin_amdgcn_sched_barrier(0);                                       \
        __builtin_amdgcn_s_barrier();                                            \
        __builtin_amdgcn_sched_barrier(0);                                       \
    }

// ================== 256x256 8-phase bf16 GEMM (K=512 fixed) ==================
// outB = A[M,512]b @ W[N,512]b^T + bias (+relu). 512 threads, 8 waves (2Mx4N),
// per-wave 128x64 output. LDS 128 KiB: 2 buf x (A 256x64 + B 256x64) bf16.
// grid: 1D, (M/256)*(N/256) blocks; 2D XCD chunking (requires (M>>8)%8==0).
__global__ __launch_bounds__(512, 2) void gemm_256(
    const unsigned short* __restrict__ A, const unsigned short* __restrict__ Wt,
    const float* __restrict__ bias, unsigned short* __restrict__ outB,
    int M, int N, int relu)
{
    __shared__ __align__(16) unsigned short Sh[65536];   // 128 KiB
    const int tid = threadIdx.x;
    const int lane = tid & 63;
    const int w = tid >> 6;              // 0..7
    const int wm = (w >> 2) * 128;       // 0 / 128
    const int wn = (w & 3) * 64;         // 0..192
    const int lr = lane & 15;
    const int quad = lane >> 4;
    const int xo0 = ((quad ^ (lr & 7)) << 3);
    const int xo1 = (((4 | quad) ^ (lr & 7)) << 3);

    // 2D XCD chunking: xcd owns m-tiles [xcd*mloc, xcd*mloc+mloc) x all n.
    const int b0 = blockIdx.x;
    const int xcd = b0 & 7, slot = b0 >> 3;
    const int mloc = (M >> 8) >> 3;
    const size_t bm = (size_t)(xcd * mloc + slot % mloc) * 256;
    const size_t bn = (size_t)(slot / mloc) * 256;

    const int ar = tid >> 3;                         // 0..63
    const int sw = ((tid & 7) ^ (ar & 7)) << 3;      // pre-swizzled k-chunk
    const unsigned short* Ag = A  + (bm + ar) * (size_t)512 + sw;
    const unsigned short* Bg = Wt + (bn + ar) * (size_t)512 + sw;
    const int ld = tid * 8;                          // LDS elem offset (16B/lane)

    frag_cd acc[8][4] = {};
    frag_ab bf[4][2];

    // prologue: 0.B0 0.B1 0.A0 0.A1 1.B0 1.B1
    STG(0,     16384, Bg, 0,   0, 512);
    STG(0,     24576, Bg, 128, 0, 512);
    STG(0,     0,     Ag, 0,   0, 512);
    STG(0,     8192,  Ag, 128, 0, 512);
    STG(32768, 16384, Bg, 0,   1, 512);
    STG(32768, 24576, Bg, 128, 1, 512);
    VMW(4);
    __builtin_amdgcn_sched_barrier(0);
    __builtin_amdgcn_s_barrier();
    __builtin_amdgcn_sched_barrier(0);

    for (int I = 0; I < 3; ++I) {
        const int tb = 2 * I + 1, tc = 2 * I + 2, td = 2 * I + 3;
        PHASE(0,     0, 1, STG(32768, 0,     Ag, 0,   tb, 512), (void)0);
        PHASE(0,     2, 0, STG(32768, 8192,  Ag, 128, tb, 512), (void)0);
        PHASE(0,     4, 0, STG(0,     16384, Bg, 0,   tc, 512), (void)0);
        PHASE(0,     6, 0, STG(0,     24576, Bg, 128, tc, 512), VMW(4));
        PHASE(32768, 0, 1, STG(0,     0,     Ag, 0,   tc, 512), (void)0);
        PHASE(32768, 2, 0, STG(0,     8192,  Ag, 128, tc, 512), (void)0);
        PHASE(32768, 4, 0, STG(32768, 16384, Bg, 0,   td, 512), (void)0);
        PHASE(32768, 6, 0, STG(32768, 24576, Bg, 128, td, 512), VMW(4));
    }
    PHASE(0,     0, 1, STG(32768, 0,    Ag, 0,   7, 512), (void)0);
    PHASE(0,     2, 0, STG(32768, 8192, Ag, 128, 7, 512), (void)0);
    PHASE(0,     4, 0, (void)0, (void)0);
    PHASE(0,     6, 0, (void)0, VMW(0));
    PHASE(32768, 0, 1, (void)0, (void)0);
    PHASE(32768, 2, 0, (void)0, (void)0);
    PHASE(32768, 4, 0, (void)0, (void)0);
    PHASE(32768, 6, 0, (void)0, (void)0);

    // epilogue: wave w stages its 128x64 to Sh[w*8192], then 16B/lane stores
    float bv[4];
#pragma unroll
    for (int j = 0; j < 4; ++j) bv[j] = bias[(int)bn + wn + j * 16 + lr];
    unsigned short* Cs = Sh + w * 8192;
#pragma unroll
    for (int m = 0; m < 8; ++m)
#pragma unroll
        for (int j = 0; j < 4; ++j)
#pragma unroll
            for (int r = 0; r < 4; ++r) {
                float v = acc[m][j][r] + bv[j];
                if (relu) v = fmaxf(v, 0.f);
                Cs[(m * 16 + quad * 4 + r) * 64 + j * 16 + lr] = f2b(v);
            }
    const int rl = lane >> 3, c8 = (lane & 7) * 8;
#pragma unroll
    for (int k = 0; k < 16; ++k) {
        const int row = rl + k * 8;
        ushort8v val = *(const ushort8v*)&Cs[row * 64 + c8];
        *(ushort8v*)(outB + (size_t)(bm + wm + row) * N + bn + wn + c8) = val;
    }
}

// ======= 256x128 4-phase GEMM, runtime N (out stride) and K ==================
// mode 0: outB = A@W^T + bias                   (QKV)
// mode 1: + f32 residual resA/resB (rows <8192 / >=8192)   (o-proj)
// mode 2: + b2f(outB) in place                  (FFN2)
// grid (M/256)*(N/128) blocks (must be %8==0), 512 thr, 8 waves 4Mx2N,
// per-wave 64x64. LDS 96 KiB: 2 buf x (A 256x64 = 32K + B 128x64 = 16K).
__global__ __launch_bounds__(512, 2) void gemm_n128(
    const unsigned short* __restrict__ A, const unsigned short* __restrict__ Wt,
    const float* __restrict__ bias,
    const float* __restrict__ resA, const float* __restrict__ resB,
    unsigned short* __restrict__ outB, int N, int K, int mode)
{
    __shared__ __align__(16) unsigned short Sh[49152];   // 96 KiB
    const int tid = threadIdx.x;
    const int lane = tid & 63;
    const int w = tid >> 6;              // 0..7
    const int wm = (w >> 1) * 64;        // 0/64/128/192
    const int wn = (w & 1) * 64;         // 0/64
    const int lr = lane & 15;
    const int quad = lane >> 4;
    const int xo0 = ((quad ^ (lr & 7)) << 3);
    const int xo1 = (((4 | quad) ^ (lr & 7)) << 3);

    // 2D XCD chunking: xcd owns 8 consecutive m-tiles x all n-tiles.
    const int b0 = blockIdx.x;
    const int xcd = b0 & 7, slot = b0 >> 3;
    const size_t bm = (size_t)(xcd * 8 + (slot & 7)) * 256;
    const size_t bn = (size_t)(slot >> 3) * 128;

    const int ar = tid >> 3;
    const int sw = ((tid & 7) ^ (ar & 7)) << 3;
    const unsigned short* Ag = A  + (bm + ar) * (size_t)K + sw;
    const unsigned short* Bg = Wt + (bn + ar) * (size_t)K + sw;
    const int ld = tid * 8;

    frag_cd acc[4][4] = {};
    frag_ab bf[4][2];

    // prologue: aB aA0 aA1 bB ; wait all but bB
    STG(0,     16384, Bg, 0,   0, K);
    STG(0,     0,     Ag, 0,   0, K);
    STG(0,     8192,  Ag, 128, 0, K);
    STG(24576, 16384, Bg, 0,   1, K);
    VMW(2);
    __builtin_amdgcn_sched_barrier(0);
    __builtin_amdgcn_s_barrier();
    __builtin_amdgcn_sched_barrier(0);

    const int nIter = K >> 7;            // 2 K-tiles per iteration
    for (int I = 0; I < nIter - 1; ++I) {
        const int tb = 2 * I + 1, tc = 2 * I + 2, td = 2 * I + 3;
        PHASE(0,     0, 1, { STG(24576, 0, Ag, 0, tb, K); STG(24576, 8192, Ag, 128, tb, K); }, (void)0);
        PHASE(0,     2, 0, STG(0, 16384, Bg, 0, tc, K), VMW(2));
        PHASE(24576, 0, 1, { STG(0, 0, Ag, 0, tc, K); STG(0, 8192, Ag, 128, tc, K); }, (void)0);
        PHASE(24576, 2, 0, STG(24576, 16384, Bg, 0, td, K), VMW(2));
    }
    {   // tail: computes tiles 2(nIter-1), 2nIter-1; only b's A left to stage
        const int tb = (K >> 6) - 1;
        PHASE(0,     0, 1, { STG(24576, 0, Ag, 0, tb, K); STG(24576, 8192, Ag, 128, tb, K); }, (void)0);
        PHASE(0,     2, 0, (void)0, VMW(0));
        PHASE(24576, 0, 1, (void)0, (void)0);
        PHASE(24576, 2, 0, (void)0, (void)0);
    }

    // epilogue: wave w stages its 64x64 to Sh[w*4096]; residual added post-LDS
    float bv[4];
#pragma unroll
    for (int j = 0; j < 4; ++j) bv[j] = bias[(int)bn + wn + j * 16 + lr];
    unsigned short* Cs = Sh + w * 4096;
#pragma unroll
    for (int m = 0; m < 4; ++m)
#pragma unroll
        for (int j = 0; j < 4; ++j)
#pragma unroll
            for (int r = 0; r < 4; ++r)
                Cs[(m * 16 + quad * 4 + r) * 64 + j * 16 + lr] = f2b(acc[m][j][r] + bv[j]);
    const int rl = lane >> 3, c8 = (lane & 7) * 8;
#pragma unroll
    for (int k = 0; k < 8; ++k) {
        const int row = rl + k * 8;
        const int grow = (int)bm + wm + row;
        const size_t idx = (size_t)grow * N + bn + wn + c8;
        ushort8v val = *(const ushort8v*)&Cs[row * 64 + c8];
        if (mode == 0) {
            *(ushort8v*)(outB + idx) = val;
            continue;
        }
        float vv[8];
#pragma unroll
        for (int t = 0; t < 8; ++t) vv[t] = b2f(val[t]);
        if (mode == 1) {
            const float* rp = (grow < 8192) ? resA + idx : resB + idx - (size_t)8192 * N;
            float4 ra = *(const float4*)(rp);
            float4 rb = *(const float4*)(rp + 4);
            vv[0] += ra.x; vv[1] += ra.y; vv[2] += ra.z; vv[3] += ra.w;
            vv[4] += rb.x; vv[5] += rb.y; vv[6] += rb.z; vv[7] += rb.w;
        } else {
            ushort8v old = *(const ushort8v*)(outB + idx);
#pragma unroll
            for (int t = 0; t < 8; ++t) vv[t] += b2f(old[t]);
        }
        ushort8v o;
#pragma unroll
        for (int t = 0; t < 8; ++t) o[t] = f2b(vv[t]);
        *(ushort8v*)(outB + idx) = o;
    }
}

// -------- merged fp32->bf16 converts + QKV bias concat --------
__global__ __launch_bounds__(256) void convert_all(
    const float* __restrict__ Wq, const float* __restrict__ Wk,
    const float* __restrict__ Wv, const float* __restrict__ Wo,
    const float* __restrict__ W1, const float* __restrict__ W2,
    const float* __restrict__ question, const float* __restrict__ query,
    const float* __restrict__ bqp, const float* __restrict__ bkp,
    const float* __restrict__ bvp,
    unsigned short* __restrict__ Wqkvb, unsigned short* __restrict__ Wob,
    unsigned short* __restrict__ W1b, unsigned short* __restrict__ W2b,
    unsigned short* __restrict__ Xb, float* __restrict__ bqkv)
{
    const int b = blockIdx.x;
    const float* src; unsigned short* dst; size_t off;
    if (b < 256)        { src = Wq; dst = Wqkvb;          off = (size_t)b * 1024; }
    else if (b < 512)   { src = Wk; dst = Wqkvb + 262144; off = (size_t)(b - 256) * 1024; }
    else if (b < 768)   { src = Wv; dst = Wqkvb + 524288; off = (size_t)(b - 512) * 1024; }
    else if (b < 1024)  { src = Wo; dst = Wob;            off = (size_t)(b - 768) * 1024; }
    else if (b < 2048)  { src = W1; dst = W1b;            off = (size_t)(b - 1024) * 1024; }
    else if (b < 3072)  { src = W2; dst = W2b;            off = (size_t)(b - 2048) * 1024; }
    else if (b < 7168)  { src = question; dst = Xb;       off = (size_t)(b - 3072) * 1024; }
    else if (b < 11264) { src = query; dst = Xb + 4194304; off = (size_t)(b - 7168) * 1024; }
    else {
        const int n = (b - 11264) * 256 + threadIdx.x;   // 0..1535
        bqkv[n] = (n < 512) ? bqp[n] : (n < 1024) ? bkp[n - 512] : bvp[n - 1024];
        return;
    }
    const size_t idx = off + threadIdx.x * 4;
    float4 v = *(const float4*)(src + idx);
    ushort4 o;
    o.x = f2b(v.x); o.y = f2b(v.y); o.z = f2b(v.z); o.w = f2b(v.w);
    *(ushort4*)(dst + idx) = o;
}

// ------- Spart[bh][slice] = sum over 256 l-rows of K^T outer V (merged QKV) ----
__global__ __launch_bounds__(256) void s_kernel(
    const unsigned short* __restrict__ QKV, float* __restrict__ Spart)
{
    const int bh = blockIdx.x;           // 0..31
    const int sl = blockIdx.y;           // 0..NSLICE-1
    const int b = bh >> 3, h = bh & 7;
    const int pass = sl >> 3;
    const int l0 = (sl & 7) * 256;
    __shared__ float Ks[64][64];
    __shared__ float Vs[64][64];
    const int tid = threadIdx.x;
    const int tx = tid & 15, ty = tid >> 4;
    const int srow = tid >> 3;
    const int scol = (tid & 7) * 8;
    const size_t rowbase = (size_t)pass * 8192 + (size_t)b * Lq + l0;

    float acc[4][4] = {};

    for (int t0 = 0; t0 < 256; t0 += 64) {
        const unsigned short* kp0 = QKV + (rowbase + t0 + srow) * 1536 + 512 + h * 64 + scol;
        const unsigned short* kp1 = kp0 + (size_t)32 * 1536;
        ushort8v k0 = *(const ushort8v*)kp0;
        ushort8v v0 = *(const ushort8v*)(kp0 + 512);
        ushort8v k1 = *(const ushort8v*)kp1;
        ushort8v v1 = *(const ushort8v*)(kp1 + 512);
        __syncthreads();
#pragma unroll
        for (int e = 0; e < 8; ++e) {
            Ks[srow][scol + e]      = b2f(k0[e]);
            Vs[srow][scol + e]      = b2f(v0[e]);
            Ks[srow + 32][scol + e] = b2f(k1[e]);
            Vs[srow + 32][scol + e] = b2f(v1[e]);
        }
        __syncthreads();
#pragma unroll 4
        for (int rr = 0; rr < 64; ++rr) {
            const float4 kf = *(const float4*)&Ks[rr][ty * 4];
            const float4 vf = *(const float4*)&Vs[rr][tx * 4];
            acc[0][0] = fmaf(kf.x, vf.x, acc[0][0]);
            acc[0][1] = fmaf(kf.x, vf.y, acc[0][1]);
            acc[0][2] = fmaf(kf.x, vf.z, acc[0][2]);
            acc[0][3] = fmaf(kf.x, vf.w, acc[0][3]);
            acc[1][0] = fmaf(kf.y, vf.x, acc[1][0]);
            acc[1][1] = fmaf(kf.y, vf.y, acc[1][1]);
            acc[1][2] = fmaf(kf.y, vf.z, acc[1][2]);
            acc[1][3] = fmaf(kf.y, vf.w, acc[1][3]);
            acc[2][0] = fmaf(kf.z, vf.x, acc[2][0]);
            acc[2][1] = fmaf(kf.z, vf.y, acc[2][1]);
            acc[2][2] = fmaf(kf.z, vf.z, acc[2][2]);
            acc[2][3] = fmaf(kf.z, vf.w, acc[2][3]);
            acc[3][0] = fmaf(kf.w, vf.x, acc[3][0]);
            acc[3][1] = fmaf(kf.w, vf.y, acc[3][1]);
            acc[3][2] = fmaf(kf.w, vf.z, acc[3][2]);
            acc[3][3] = fmaf(kf.w, vf.w, acc[3][3]);
        }
    }

    float* Sp = Spart + ((size_t)bh * NSLICE + sl) * 4096;
#pragma unroll
    for (int i = 0; i < 4; ++i) {
        float4 o = make_float4(acc[i][0], acc[i][1], acc[i][2], acc[i][3]);
        *(float4*)(Sp + (ty * 4 + i) * 64 + tx * 4) = o;
    }
}

// ------- reduce NSLICE partials -> Sbt bf16, B-layout [bh][khalf][n][kj] -------
__global__ __launch_bounds__(256) void sbt_convert(
    const float* __restrict__ Spart, unsigned short* __restrict__ Sbt)
{
    const int bh = blockIdx.x;
    const int uo = blockIdx.y;           // 0..3
    const float* Sp = Spart + (size_t)bh * (NSLICE * 4096);
    unsigned short* Dp = Sbt + (size_t)bh * 4096;
    const int t = threadIdx.x;
#pragma unroll
    for (int u = 0; u < 4; ++u) {
        const int d = (uo * 4 + u) * 256 + t;
        float v = 0.f;
#pragma unroll
        for (int s = 0; s < NSLICE; ++s) v += Sp[(size_t)s * 4096 + d];
        const int row = d >> 6, col = d & 63;
        Dp[(row >> 5) * 2048 + col * 32 + (row & 31)] = f2b(v);
    }
}

// ------- attn = Q @ S_bh via MFMA; block: 128 rows x 64 cols (one head) -------
__global__ __launch_bounds__(256) void attn_mfma(
    const unsigned short* __restrict__ QKV, const unsigned short* __restrict__ Sbt,
    unsigned short* __restrict__ Ob)
{
    __shared__ __align__(16) unsigned short Sh[2 * 128 * 32 + 2 * 64 * 32];
    unsigned short* At = Sh;
    unsigned short* Bt = Sh + 2 * 128 * 32;
    const int h = blockIdx.x;
    const int rbase = blockIdx.y * 128;
    const int b = (rbase >> 11) & 3;
    const int bh = b * 8 + h;
    const int tid = threadIdx.x;
    const int lane = tid & 63;
    const int w = tid >> 6;
    const int lr = lane & 15;
    const int quad = lane >> 4;

    {
        const int rloc = tid >> 2, c8 = (tid & 3) * 8;
#pragma unroll
        for (int it = 0; it < 4; ++it) {
            const int kk = it & 1, rh = it >> 1;
            const unsigned short* g = QKV +
                ((size_t)rbase + rh * 64 + rloc) * 1536 + h * 64 + kk * 32 + c8;
            GLD16(g, At + kk * 4096 + rh * 2048 + w * 512);
        }
        const unsigned short* Sg = Sbt + (size_t)bh * 4096 + tid * 8;
#pragma unroll
        for (int bi = 0; bi < 2; ++bi)
            GLD16(Sg + bi * 2048, Bt + bi * 2048 + w * 512);
    }
    __syncthreads();

    frag_cd acc[2][4] = {};
#pragma unroll
    for (int kk = 0; kk < 2; ++kk) {
        frag_ab a[2], bfr[4];
#pragma unroll
        for (int i = 0; i < 2; ++i)
            a[i] = *(const frag_ab*)&At[kk * 4096 + (w * 32 + i * 16 + lr) * 32 + quad * 8];
#pragma unroll
        for (int j = 0; j < 4; ++j)
            bfr[j] = *(const frag_ab*)&Bt[kk * 2048 + (j * 16 + lr) * 32 + quad * 8];
#pragma unroll
        for (int i = 0; i < 2; ++i)
#pragma unroll
            for (int j = 0; j < 4; ++j)
                acc[i][j] = __builtin_amdgcn_mfma_f32_16x16x32_bf16(a[i], bfr[j], acc[i][j], 0, 0, 0);
    }

    __syncthreads();
    unsigned short* Cs = Sh + w * 2048;
#pragma unroll
    for (int i = 0; i < 2; ++i)
#pragma unroll
        for (int j = 0; j < 4; ++j)
#pragma unroll
            for (int r = 0; r < 4; ++r)
                Cs[(i * 16 + quad * 4 + r) * 64 + j * 16 + lr] = f2b(acc[i][j][r]);
    const int rl = lane >> 3;
    const int c8o = (lane & 7) * 8;
#pragma unroll
    for (int k = 0; k < 4; ++k) {
        const int row = rl + k * 8;
        ushort8v val = *(const ushort8v*)&Cs[row * 64 + c8o];
        *(ushort8v*)(Ob + (size_t)(rbase + w * 32 + row) * 512 + h * 64 + c8o) = val;
    }
}

// ------- LN over bf16 row (512) in place; wave-shuffle reduction -------
__global__ __launch_bounds__(256) void ln_b16_inplace(
    unsigned short* __restrict__ Y, const float* __restrict__ g,
    const float* __restrict__ bta)
{
    __shared__ float part[8];
    const int row = blockIdx.x;
    const int t = threadIdx.x;
    const int w = t >> 6;
    unsigned short* yr = Y + (size_t)row * Dq;
    const float v0 = b2f(yr[t]), v1 = b2f(yr[t + 256]);
    float s = v0 + v1;
#pragma unroll
    for (int off = 32; off; off >>= 1) s += __shfl_xor(s, off, 64);
    if ((t & 63) == 0) part[w] = s;
    __syncthreads();
    const float mean = (part[0] + part[1] + part[2] + part[3]) * (1.f / Dq);
    const float d0 = v0 - mean, d1 = v1 - mean;
    float q = d0 * d0 + d1 * d1;
#pragma unroll
    for (int off = 32; off; off >>= 1) q += __shfl_xor(q, off, 64);
    if ((t & 63) == 0) part[4 + w] = q;
    __syncthreads();
    const float rstd = rsqrtf((part[4] + part[5] + part[6] + part[7]) * (1.f / Dq) + 1e-5f);
    yr[t] = f2b(d0 * rstd * g[t] + bta[t]);
    yr[t + 256] = f2b(d1 * rstd * g[t + 256] + bta[t + 256]);
}

// ------- LN over bf16 row -> out f32 half-columns (merged rows) -------
__global__ __launch_bounds__(256) void ln_b16_out(
    const unsigned short* __restrict__ Y, const float* __restrict__ g,
    const float* __restrict__ bta, float* __restrict__ out)
{
    __shared__ float part[8];
    const int row = blockIdx.x;
    const int t = threadIdx.x;
    const int w = t >> 6;
    const unsigned short* yr = Y + (size_t)row * Dq;
    const float v0 = b2f(yr[t]), v1 = b2f(yr[t + 256]);
    float s = v0 + v1;
#pragma unroll
    for (int off = 32; off; off >>= 1) s += __shfl_xor(s, off, 64);
    if ((t & 63) == 0) part[w] = s;
    __syncthreads();
    const float mean = (part[0] + part[1] + part[2] + part[3]) * (1.f / Dq);
    const float d0 = v0 - mean, d1 = v1 - mean;
    float q = d0 * d0 + d1 * d1;
#pragma unroll
    for (int off = 32; off; off >>= 1) q += __shfl_xor(q, off, 64);
    if ((t & 63) == 0) part[4 + w] = q;
    __syncthreads();
    const float rstd = rsqrtf((part[4] + part[5] + part[6] + part[7]) * (1.f / Dq) + 1e-5f);
    const int half = row >> 13, br = row & 8191;
    float* orow = out + (size_t)br * 1024 + half * 512;
    orow[t] = d0 * rstd * g[t] + bta[t];
    orow[t + 256] = d1 * rstd * g[t + 256] + bta[t + 256];
}

extern "C" void kernel_launch(void* const* d_in, const int* in_sizes, int n_in,
                              void* d_out, int out_size, void* d_ws, size_t ws_size,
                              hipStream_t stream)
{
    const float* question = (const float*)d_in[0];
    const float* query    = (const float*)d_in[1];
    const float* Wq = (const float*)d_in[2];  const float* bqp = (const float*)d_in[3];
    const float* Wk = (const float*)d_in[4];  const float* bkp = (const float*)d_in[5];
    const float* Wv = (const float*)d_in[6];  const float* bvp = (const float*)d_in[7];
    const float* Wo = (const float*)d_in[8];  const float* bo  = (const float*)d_in[9];
    const float* ln_g = (const float*)d_in[10]; const float* ln_b = (const float*)d_in[11];
    const float* W1 = (const float*)d_in[12]; const float* b1 = (const float*)d_in[13];
    const float* W2 = (const float*)d_in[14]; const float* b2 = (const float*)d_in[15];
    float* out = (float*)d_out;
    char* ws = (char*)d_ws;

    // ---- workspace (~87 MiB) ----
    unsigned short* QKVb  = (unsigned short*)(ws);
    unsigned short* attnb = (unsigned short*)(ws + 48 * MiBu);
    float* Spart          = (float*)(ws + 48 * MiBu);           // dead before attnb
    unsigned short* Xb    = (unsigned short*)(ws + 64 * MiBu);
    unsigned short* xbuf  = (unsigned short*)(ws + 64 * MiBu);  // y0b -> xb -> y
    unsigned short* hb    = (unsigned short*)(ws);              // [16384,2048] bf16
    char* wp = ws + 80 * MiBu + 524288;
    unsigned short* Wqkvb = (unsigned short*)wp;  wp += 1536 * 512 * 2;
    unsigned short* Wob   = (unsigned short*)wp;  wp += 512 * 512 * 2;
    unsigned short* W1b   = (unsigned short*)wp;  wp += 2048 * 512 * 2;
    unsigned short* W2b   = (unsigned short*)wp;  wp += 512 * 2048 * 2;
    unsigned short* Sbt   = (unsigned short*)wp;  wp += 32 * 4096 * 2;
    float* bqkv           = (float*)wp;

    dim3 blk(256);

    convert_all<<<11270, blk, 0, stream>>>(Wq, Wk, Wv, Wo, W1, W2, question, query,
                                           bqp, bkp, bvp,
                                           Wqkvb, Wob, W1b, W2b, Xb, bqkv);

    // QKV: [16384,512]@[1536,512]^T -> bf16 (256x128 4-phase; 768 blocks = 3 rounds)
    gemm_n128<<<dim3(768), dim3(512), 0, stream>>>(Xb, Wqkvb, bqkv,
                                                   nullptr, nullptr, QKVb,
                                                   1536, 512, 0);

    // S partials (fp32, no atomics) -> reduce+pack bf16 B-layout; attn via MFMA
    s_kernel<<<dim3(32, NSLICE), blk, 0, stream>>>(QKVb, Spart);
    sbt_convert<<<dim3(32, 4), blk, 0, stream>>>(Spart, Sbt);
    attn_mfma<<<dim3(8, 128), blk, 0, stream>>>(QKVb, Sbt, attnb);

    // o-proj + residual(inputs) + bo -> bf16 y0b (256x128 4-phase, 256 blocks)
    gemm_n128<<<dim3(256), dim3(512), 0, stream>>>(attnb, Wob, bo,
                                                   question, query, xbuf,
                                                   512, 512, 1);

    // LN1 in place: xb = LN(y0b)
    ln_b16_inplace<<<Mrows, blk, 0, stream>>>(xbuf, ln_g, ln_b);

    // FFN1 full-M: h = relu(xb @ W1^T + b1) -> bf16 [16384,2048] (256^2 8-phase)
    gemm_256<<<dim3(512), dim3(512), 0, stream>>>(xbuf, W1b, b1, hb,
                                                  Mrows, PFq, 1);

    // FFN2 full-M, K=2048: y = h @ W2^T + b2 + xb, bf16 in place (256 blocks)
    gemm_n128<<<dim3(256), dim3(512), 0, stream>>>(hb, W2b, b2,
                                                   nullptr, nullptr, xbuf,
                                                   512, 2048, 2);

    // LN2 -> out halves
    ln_b16_out<<<Mrows, blk, 0, stream>>>(xbuf, ln_g, ln_b, out);
}